// Round 1
// 390.581 us; speedup vs baseline: 1.0191x; 1.0191x over previous
//
#include <hip/hip_runtime.h>

// ---------------------------------------------------------------------------
// LinearAttention (FAVOR-style), all GEMMs as bf16 MFMA 16x16x32, m97-style:
//   cvtx:  x fp32 -> xb[b][l][d] bf16  AND  xT[b][d][l] bf16 (one read of x)
//          register 4x4 transpose + halfchunk-XOR-swizzled LDS (conflict-free)
//   cvtw:  qw,kw fp32 -> wt[n][k] bf16 (n in [0,512): q cols then k cols)
//   proj:  C = x @ W (128x128 tile, BK=64, global_load_lds + XOR-swizzled LDS)
//          q-half -> exp -> qp[m][e]; k-half -> exp -> kT[b][e][l] (transposed)
//   zinv:  1/(rowsum(qp)+1e-8)
//   kv:    kT @ x  (K-split 4, fp32 partials)  -> kvreduce -> kvT[b][d][e]
//   out:   (qp @ kv) * zinv
// ---------------------------------------------------------------------------

#define EMBED 1024
#define PROJ  256
#define LSEQ  4096
#define BATCH 8

typedef short  bfrag __attribute__((ext_vector_type(8)));  // 8 bf16 = 1 MFMA frag
typedef float  f4    __attribute__((ext_vector_type(4)));
typedef unsigned short u16x8 __attribute__((ext_vector_type(8)));
typedef unsigned short u16x4 __attribute__((ext_vector_type(4)));

static __device__ __forceinline__ unsigned short f2bf(float f) {
  unsigned int u = __builtin_bit_cast(unsigned int, f);
  u += 0x7fffu + ((u >> 16) & 1u);  // RNE
  return (unsigned short)(u >> 16);
}
static __device__ __forceinline__ float bf2f(unsigned short h) {
  unsigned int u = ((unsigned int)h) << 16;
  return __builtin_bit_cast(float, u);
}

// async global->LDS, 16 B per lane; LDS dest = wave-uniform base + lane*16
static __device__ __forceinline__ void gload_lds16(const void* g, void* l) {
  __builtin_amdgcn_global_load_lds(
      (__attribute__((address_space(1))) void*)(unsigned long long)(g),
      (__attribute__((address_space(3))) void*)(unsigned)(unsigned long long)(l),
      16, 0, 0);
}

// Stage a 128x64 bf16 tile. LDS layout: row-major rows of 8 16B-chunks,
// chunk stored at position p = c ^ (r&7)  (XOR swizzle: conflict-free b128
// frag reads, and LDS dest stays lane-sequential for global_load_lds).
static __device__ __forceinline__ void stage_tile(
    const unsigned short* __restrict__ src, int row0, int stride, int k0,
    unsigned short* lds, int wave, int lane) {
#pragma unroll
  for (int j = 0; j < 4; j++) {
    int slot = (wave * 4 + j) * 64 + lane;
    int r = slot >> 3, cp = slot & 7;
    int c = cp ^ (r & 7);
    gload_lds16(src + (size_t)(row0 + r) * stride + k0 + c * 8,
                lds + (wave * 4 + j) * 512);
  }
}

// read one 16B MFMA fragment from the swizzled tile
static __device__ __forceinline__ bfrag read_frag(const unsigned short* lds,
                                                  int row, int chunk) {
  return *(const bfrag*)(lds + ((row << 3) + (chunk ^ (row & 7))) * 8);
}

// ---------------------------------------------------------------------------
// cvtx: x fp32 [b][l][d] -> xb bf16 [b][l][d] + xT bf16 [b][d][l]
// Register 4x4 transpose; LDS [64][64] u16, 8B-halfchunk XOR swizzle:
//   halfchunk h (4 shorts) of row d stored at h' = h ^ ((d&7)<<1).
// Phase-1 stores: 16 distinct even start-banks x 4 lanes = conflict-free.
// Phase-2 reads:  chunk c read at c^(d&7), 8 starts x 8 lanes = conflict-free.
// ---------------------------------------------------------------------------
__global__ __launch_bounds__(256) void cvtx_kernel(
    const float* __restrict__ x, unsigned short* __restrict__ xb,
    unsigned short* __restrict__ xT) {
  __shared__ unsigned short T[64 * 64];
  const int tid = threadIdx.x;
  const int d0 = blockIdx.x * 64, l0 = blockIdx.y * 64, b = blockIdx.z;
  const int br = tid & 15;   // l sub-block (4 rows)
  const int bcq = tid >> 4;  // d sub-block (4 cols)

  unsigned short h[4][4];
#pragma unroll
  for (int i = 0; i < 4; i++) {
    const size_t row = (size_t)(b * LSEQ + l0 + br * 4 + i) * EMBED + d0 + bcq * 4;
    f4 v = *(const f4*)(x + row);
    u16x4 hv = (u16x4){f2bf(v[0]), f2bf(v[1]), f2bf(v[2]), f2bf(v[3])};
    *(u16x4*)(xb + row) = hv;
#pragma unroll
    for (int k = 0; k < 4; k++) h[i][k] = hv[k];
  }
#pragma unroll
  for (int k = 0; k < 4; k++) {
    int dd = bcq * 4 + k;
    int hp = br ^ ((dd & 7) << 1);
    *(u16x4*)(T + dd * 64 + hp * 4) = (u16x4){h[0][k], h[1][k], h[2][k], h[3][k]};
  }
  __syncthreads();
#pragma unroll
  for (int it = 0; it < 2; it++) {
    int slot = it * 256 + tid;
    int dd = slot >> 3, ch = slot & 7;
    int cc = ch ^ (dd & 7);
    *(u16x8*)(xT + ((size_t)(b * EMBED + d0 + dd)) * LSEQ + l0 + ch * 8) =
        *(const u16x8*)(T + dd * 64 + cc * 8);
  }
}

// ---------------------------------------------------------------------------
// cvtw: qw/kw fp32 [k][n] -> wt bf16 [n][k], n in [0,512) = [q | k]
// ---------------------------------------------------------------------------
__global__ __launch_bounds__(256) void cvtw_kernel(
    const float* __restrict__ qw, const float* __restrict__ kw,
    unsigned short* __restrict__ wt) {
  __shared__ unsigned short T[64][72];
  const int tid = threadIdx.x;
  const int n0 = blockIdx.x * 64, k0 = blockIdx.y * 64;
  const float* W = blockIdx.z ? kw : qw;
#pragma unroll
  for (int it = 0; it < 4; it++) {
    int slot = it * 256 + tid;
    int r = slot >> 4, c4 = slot & 15;  // r: k-local, c4: n-chunk
    f4 v = *(const f4*)(W + (size_t)(k0 + r) * PROJ + n0 + c4 * 4);
#pragma unroll
    for (int j = 0; j < 4; j++) T[c4 * 4 + j][r] = f2bf(v[j]);
  }
  __syncthreads();
#pragma unroll
  for (int it = 0; it < 2; it++) {
    int slot = it * 256 + tid;
    int n = slot >> 3, ch = slot & 7;
    *(u16x8*)(wt + ((size_t)(blockIdx.z * PROJ + n0 + n)) * EMBED + k0 + ch * 8) =
        *(const u16x8*)&T[n][ch * 8];
  }
}

// ---------------------------------------------------------------------------
// proj: C[m][n] = exp(xb @ wt^T). M=32768, N=512, K=1024. 128x128 tile, BK=64.
// ---------------------------------------------------------------------------
__global__ __launch_bounds__(256) void proj_kernel(
    const unsigned short* __restrict__ xb, const unsigned short* __restrict__ wt,
    unsigned short* __restrict__ qp, unsigned short* __restrict__ kT) {
  __shared__ union {
    struct { unsigned short A[128 * 64]; unsigned short B[128 * 64]; } t;
    unsigned short T[128 * 136];
  } sm;
  const int tid = threadIdx.x, wave = tid >> 6, lane = tid & 63;
  const int quad = lane >> 4, l16 = lane & 15;
  const int wm = wave >> 1, wn = wave & 1;
  const int n0 = blockIdx.x * 128, m0 = blockIdx.y * 128;

  f4 acc[4][4];
#pragma unroll
  for (int i = 0; i < 4; i++)
#pragma unroll
    for (int j = 0; j < 4; j++) acc[i][j] = (f4){0.f, 0.f, 0.f, 0.f};

  for (int k0 = 0; k0 < EMBED; k0 += 64) {
    stage_tile(xb, m0, EMBED, k0, sm.t.A, wave, lane);
    stage_tile(wt, n0, EMBED, k0, sm.t.B, wave, lane);
    __syncthreads();
#pragma unroll
    for (int ks = 0; ks < 2; ks++) {
      bfrag a[4], bfr[4];
#pragma unroll
      for (int mt = 0; mt < 4; mt++)
        a[mt] = read_frag(sm.t.A, wm * 64 + mt * 16 + l16, ks * 4 + quad);
#pragma unroll
      for (int nt = 0; nt < 4; nt++)
        bfr[nt] = read_frag(sm.t.B, wn * 64 + nt * 16 + l16, ks * 4 + quad);
#pragma unroll
      for (int mt = 0; mt < 4; mt++)
#pragma unroll
        for (int nt = 0; nt < 4; nt++)
          acc[mt][nt] = __builtin_amdgcn_mfma_f32_16x16x32_bf16(
              a[mt], bfr[nt], acc[mt][nt], 0, 0, 0);
    }
    __syncthreads();
  }

  if (n0 < PROJ) {
    // q-half: T[l][e], then coalesced rows into qp[m][e]
#pragma unroll
    for (int mt = 0; mt < 4; mt++)
#pragma unroll
      for (int nt = 0; nt < 4; nt++)
#pragma unroll
        for (int r = 0; r < 4; r++)
          sm.T[(wm * 64 + mt * 16 + quad * 4 + r) * 136 + wn * 64 + nt * 16 + l16] =
              f2bf(__expf(acc[mt][nt][r]));
    __syncthreads();
#pragma unroll
    for (int it = 0; it < 8; it++) {
      int slot = it * 256 + tid;
      int row = slot >> 4, ch = slot & 15;
      *(u16x8*)(qp + (size_t)(m0 + row) * PROJ + n0 + ch * 8) =
          *(const u16x8*)&sm.T[row * 136 + ch * 8];
    }
  } else {
    // k-half: T[e][l], then coalesced rows into kT[b][e][l]
#pragma unroll
    for (int mt = 0; mt < 4; mt++)
#pragma unroll
      for (int nt = 0; nt < 4; nt++) {
        u16x4 h;
#pragma unroll
        for (int r = 0; r < 4; r++) h[r] = f2bf(__expf(acc[mt][nt][r]));
        *(u16x4*)&sm.T[(wn * 64 + nt * 16 + l16) * 136 + wm * 64 + mt * 16 + quad * 4] = h;
      }
    __syncthreads();
    const int bb = m0 >> 12, l0 = m0 & 4095, ebase = n0 - PROJ;
#pragma unroll
    for (int it = 0; it < 8; it++) {
      int slot = it * 256 + tid;
      int e = slot >> 4, ch = slot & 15;
      *(u16x8*)(kT + (size_t)(bb * PROJ + ebase + e) * LSEQ + l0 + ch * 8) =
          *(const u16x8*)&sm.T[e * 136 + ch * 8];
    }
  }
}

// ---------------------------------------------------------------------------
// zinv[m] = 1 / (sum_e qp[m][e] + 1e-8)
// ---------------------------------------------------------------------------
__global__ __launch_bounds__(256) void zinv_kernel(
    const unsigned short* __restrict__ qp, float* __restrict__ zinv) {
  int m = blockIdx.x * 4 + (threadIdx.x >> 6);
  int lane = threadIdx.x & 63;
  u16x4 h = *(const u16x4*)(qp + (size_t)m * PROJ + lane * 4);
  float s = bf2f(h[0]) + bf2f(h[1]) + bf2f(h[2]) + bf2f(h[3]);
#pragma unroll
  for (int off = 32; off; off >>= 1) s += __shfl_xor(s, off);
  if (lane == 0) zinv[m] = 1.0f / (s + 1e-8f);
}

// ---------------------------------------------------------------------------
// kv: kvp[split][b][e][d] = sum_{l in chunk} kT[b][e][l] * xT[b][d][l]
// 128x128 tile, BK=64, K-chunk=1024 (split 4).
// ---------------------------------------------------------------------------
__global__ __launch_bounds__(256) void kv_kernel(
    const unsigned short* __restrict__ kT, const unsigned short* __restrict__ xT,
    float* __restrict__ kvp) {
  __shared__ struct { unsigned short A[128 * 64]; unsigned short B[128 * 64]; } sm;
  const int tid = threadIdx.x, wave = tid >> 6, lane = tid & 63;
  const int quad = lane >> 4, l16 = lane & 15;
  const int wm = wave >> 1, wn = wave & 1;
  const int d0 = blockIdx.x * 128, e0 = blockIdx.y * 128;
  const int b = blockIdx.z & 7, split = blockIdx.z >> 3;
  const unsigned short* As = kT + (size_t)b * PROJ * LSEQ;
  const unsigned short* Bs = xT + (size_t)b * EMBED * LSEQ;

  f4 acc[4][4];
#pragma unroll
  for (int i = 0; i < 4; i++)
#pragma unroll
    for (int j = 0; j < 4; j++) acc[i][j] = (f4){0.f, 0.f, 0.f, 0.f};

  const int kbase = split * 1024;
  for (int kk = 0; kk < 1024; kk += 64) {
    stage_tile(As, e0, LSEQ, kbase + kk, sm.A, wave, lane);
    stage_tile(Bs, d0, LSEQ, kbase + kk, sm.B, wave, lane);
    __syncthreads();
#pragma unroll
    for (int ks = 0; ks < 2; ks++) {
      bfrag a[4], bfr[4];
#pragma unroll
      for (int mt = 0; mt < 4; mt++)
        a[mt] = read_frag(sm.A, wm * 64 + mt * 16 + l16, ks * 4 + quad);
#pragma unroll
      for (int nt = 0; nt < 4; nt++)
        bfr[nt] = read_frag(sm.B, wn * 64 + nt * 16 + l16, ks * 4 + quad);
#pragma unroll
      for (int mt = 0; mt < 4; mt++)
#pragma unroll
        for (int nt = 0; nt < 4; nt++)
          acc[mt][nt] = __builtin_amdgcn_mfma_f32_16x16x32_bf16(
              a[mt], bfr[nt], acc[mt][nt], 0, 0, 0);
    }
    __syncthreads();
  }

#pragma unroll
  for (int mt = 0; mt < 4; mt++)
#pragma unroll
    for (int nt = 0; nt < 4; nt++)
#pragma unroll
      for (int r = 0; r < 4; r++) {
        int e = e0 + wm * 64 + mt * 16 + quad * 4 + r;
        int d = d0 + wn * 64 + nt * 16 + l16;
        kvp[((size_t)(split * 8 + b) * PROJ + e) * EMBED + d] = acc[mt][nt][r];
      }
}

// ---------------------------------------------------------------------------
// kvreduce: kvT[b][d][e] bf16 = f2bf( sum_split kvp[split][b][e][d] )
// ---------------------------------------------------------------------------
__global__ __launch_bounds__(256) void kvreduce_kernel(
    const float* __restrict__ kvp, unsigned short* __restrict__ kvT) {
  __shared__ float T[64][68];
  const int tid = threadIdx.x;
  const int d0 = blockIdx.x * 64, e0 = blockIdx.y * 64, b = blockIdx.z;
#pragma unroll
  for (int it = 0; it < 4; it++) {
    int slot = it * 256 + tid;
    int e = slot >> 4, c4 = slot & 15;
    f4 s = (f4){0.f, 0.f, 0.f, 0.f};
#pragma unroll
    for (int sp = 0; sp < 4; sp++)
      s += *(const f4*)(kvp + ((size_t)(sp * 8 + b) * PROJ + e0 + e) * EMBED + d0 + c4 * 4);
#pragma unroll
    for (int j = 0; j < 4; j++) T[c4 * 4 + j][e] = s[j];
  }
  __syncthreads();
#pragma unroll
  for (int it = 0; it < 2; it++) {
    int slot = it * 256 + tid;
    int d = slot >> 3, ch = slot & 7;
    u16x8 h;
#pragma unroll
    for (int j = 0; j < 8; j++) h[j] = f2bf(T[d][ch * 8 + j]);
    *(u16x8*)(kvT + ((size_t)(b * EMBED + d0 + d)) * PROJ + e0 + ch * 8) = h;
  }
}

// ---------------------------------------------------------------------------
// out: out[b][l][d] = (qp[b][l][:] @ kv[b][:][d]) * zinv[b][l]
// A = qp [l][e], B = kvT [d][e]. 128x128 tile, BK=64, K=256.
// ---------------------------------------------------------------------------
__global__ __launch_bounds__(256) void out_kernel(
    const unsigned short* __restrict__ qp, const unsigned short* __restrict__ kvT,
    const float* __restrict__ zinv, float* __restrict__ out) {
  __shared__ struct { unsigned short A[128 * 64]; unsigned short B[128 * 64]; } sm;
  __shared__ float zv[128];
  const int tid = threadIdx.x, wave = tid >> 6, lane = tid & 63;
  const int quad = lane >> 4, l16 = lane & 15;
  const int wm = wave >> 1, wn = wave & 1;
  const int d0 = blockIdx.x * 128, l0 = blockIdx.y * 128, b = blockIdx.z;
  const unsigned short* As = qp + (size_t)b * LSEQ * PROJ;
  const unsigned short* Bs = kvT + (size_t)b * EMBED * PROJ;

  if (tid < 128) zv[tid] = zinv[b * LSEQ + l0 + tid];

  f4 acc[4][4];
#pragma unroll
  for (int i = 0; i < 4; i++)
#pragma unroll
    for (int j = 0; j < 4; j++) acc[i][j] = (f4){0.f, 0.f, 0.f, 0.f};

  for (int k0 = 0; k0 < PROJ; k0 += 64) {
    stage_tile(As, l0, PROJ, k0, sm.A, wave, lane);
    stage_tile(Bs, d0, PROJ, k0, sm.B, wave, lane);
    __syncthreads();
#pragma unroll
    for (int ks = 0; ks < 2; ks++) {
      bfrag a[4], bfr[4];
#pragma unroll
      for (int mt = 0; mt < 4; mt++)
        a[mt] = read_frag(sm.A, wm * 64 + mt * 16 + l16, ks * 4 + quad);
#pragma unroll
      for (int nt = 0; nt < 4; nt++)
        bfr[nt] = read_frag(sm.B, wn * 64 + nt * 16 + l16, ks * 4 + quad);
#pragma unroll
      for (int mt = 0; mt < 4; mt++)
#pragma unroll
        for (int nt = 0; nt < 4; nt++)
          acc[mt][nt] = __builtin_amdgcn_mfma_f32_16x16x32_bf16(
              a[mt], bfr[nt], acc[mt][nt], 0, 0, 0);
    }
    __syncthreads();
  }

#pragma unroll
  for (int mt = 0; mt < 4; mt++)
#pragma unroll
    for (int nt = 0; nt < 4; nt++)
#pragma unroll
      for (int r = 0; r < 4; r++) {
        int row = wm * 64 + mt * 16 + quad * 4 + r;
        int d = d0 + wn * 64 + nt * 16 + l16;
        out[((size_t)(b * LSEQ + l0 + row)) * EMBED + d] = acc[mt][nt][r] * zv[row];
      }
}

// ---------------------------------------------------------------------------
// Workspace layout (bytes):
//   xb   @ 0          67,108,864   (bf16 [b][l][d]) -- aliased by kvp later
//   xT   @ 67108864   67,108,864   (bf16 [b][d][l])
//   wt   @ 134217728   1,048,576   (bf16 [n][k], n=[q|k])
//   qp   @ 135266304  16,777,216   (bf16 [m][e])
//   kT   @ 152043520  16,777,216   (bf16 [b][e][l])
//   kvT  @ 168820736   4,194,304   (bf16 [b][d][e])
//   zinv @ 173015040     131,072
//   kvp = xb region (33,554,432 = 4 splits * 8 * 256 * 1024 * 4)  [xb dead]
// total ~165 MB
// ---------------------------------------------------------------------------
extern "C" void kernel_launch(void* const* d_in, const int* in_sizes, int n_in,
                              void* d_out, int out_size, void* d_ws, size_t ws_size,
                              hipStream_t stream) {
  const float* x  = (const float*)d_in[0];
  const float* qw = (const float*)d_in[1];
  const float* kw = (const float*)d_in[2];
  float* out = (float*)d_out;

  char* ws = (char*)d_ws;
  unsigned short* xb   = (unsigned short*)(ws);
  unsigned short* xT   = (unsigned short*)(ws + 67108864);
  unsigned short* wt   = (unsigned short*)(ws + 134217728);
  unsigned short* qp   = (unsigned short*)(ws + 135266304);
  unsigned short* kT   = (unsigned short*)(ws + 152043520);
  unsigned short* kvT  = (unsigned short*)(ws + 168820736);
  float*          zinv = (float*)(ws + 173015040);
  float*          kvp  = (float*)(ws);  // aliases xb (dead after proj)

  cvtx_kernel<<<dim3(16, 64, 8), 256, 0, stream>>>(x, xb, xT);
  cvtw_kernel<<<dim3(4, 16, 2), 256, 0, stream>>>(qw, kw, wt);
  proj_kernel<<<dim3(4, 256), 256, 0, stream>>>(xb, wt, qp, kT);
  zinv_kernel<<<dim3(8192), 256, 0, stream>>>(qp, zinv);
  kv_kernel<<<dim3(8, 2, 32), 256, 0, stream>>>(kT, xT, kvp);
  kvreduce_kernel<<<dim3(16, 4, 8), 256, 0, stream>>>(kvp, kvT);
  out_kernel<<<dim3(8, 32, 8), 256, 0, stream>>>(qp, kvT, zinv, out);
}

// Round 2
// 388.756 us; speedup vs baseline: 1.0238x; 1.0047x over previous
//
#include <hip/hip_runtime.h>

// ---------------------------------------------------------------------------
// LinearAttention (FAVOR-style), all GEMMs as bf16 MFMA 16x16x32, m97-style:
//   cvtx:  x fp32 -> xb[b][l][d] bf16  AND  xT[b][d][l] bf16 (one read of x)
//          coalesced global + 8B-granule XOR-swizzled LDS transpose
//   cvtw:  qw,kw fp32 -> wt[n][k] bf16 (n in [0,512): q cols then k cols)
//   proj:  C = x @ W (128x128 tile, BK=64, global_load_lds + XOR-swizzled LDS)
//          q-half -> exp -> qp[m][e]; k-half -> exp -> kT[b][e][l] (transposed)
//   zinv:  1/(rowsum(qp)+1e-8)
//   kv:    kT @ x  (K-split 4, fp32 partials)  -> kvreduce -> kvT[b][d][e]
//   out:   (qp @ kv) * zinv
// ---------------------------------------------------------------------------

#define EMBED 1024
#define PROJ  256
#define LSEQ  4096
#define BATCH 8

typedef short  bfrag __attribute__((ext_vector_type(8)));  // 8 bf16 = 1 MFMA frag
typedef float  f4    __attribute__((ext_vector_type(4)));
typedef unsigned short u16x8 __attribute__((ext_vector_type(8)));
typedef unsigned short u16x4 __attribute__((ext_vector_type(4)));

static __device__ __forceinline__ unsigned short f2bf(float f) {
  unsigned int u = __builtin_bit_cast(unsigned int, f);
  u += 0x7fffu + ((u >> 16) & 1u);  // RNE
  return (unsigned short)(u >> 16);
}
static __device__ __forceinline__ float bf2f(unsigned short h) {
  unsigned int u = ((unsigned int)h) << 16;
  return __builtin_bit_cast(float, u);
}

// async global->LDS, 16 B per lane; LDS dest = wave-uniform base + lane*16
static __device__ __forceinline__ void gload_lds16(const void* g, void* l) {
  __builtin_amdgcn_global_load_lds(
      (__attribute__((address_space(1))) void*)(unsigned long long)(g),
      (__attribute__((address_space(3))) void*)(unsigned)(unsigned long long)(l),
      16, 0, 0);
}

// Stage a 128x64 bf16 tile. LDS layout: row-major rows of 8 16B-chunks,
// chunk stored at position p = c ^ (r&7)  (XOR swizzle: conflict-free b128
// frag reads, and LDS dest stays lane-sequential for global_load_lds).
static __device__ __forceinline__ void stage_tile(
    const unsigned short* __restrict__ src, int row0, int stride, int k0,
    unsigned short* lds, int wave, int lane) {
#pragma unroll
  for (int j = 0; j < 4; j++) {
    int slot = (wave * 4 + j) * 64 + lane;
    int r = slot >> 3, cp = slot & 7;
    int c = cp ^ (r & 7);
    gload_lds16(src + (size_t)(row0 + r) * stride + k0 + c * 8,
                lds + (wave * 4 + j) * 512);
  }
}

// read one 16B MFMA fragment from the swizzled tile
static __device__ __forceinline__ bfrag read_frag(const unsigned short* lds,
                                                  int row, int chunk) {
  return *(const bfrag*)(lds + ((row << 3) + (chunk ^ (row & 7))) * 8);
}

// ---------------------------------------------------------------------------
// cvtx: x fp32 [b][l][d] -> xb bf16 [b][l][d] + xT bf16 [b][d][l]
// Coalesced global both phases. LDS [64][64] u16 transpose tile with
// 8B-granule XOR swizzle: value (d,r) at d*64 + ((r>>2)^(d>>2))*4 + (r&3).
// Phase-1 scalar u16 writes: banks = 2*((r>>2)^c4)+rowbit -> 32 banks,
//   2 lanes/bank sharing one dword -> conflict-free.
// Phase-2 b64 reads: 16 distinct granule starts -> uniform 4 dw/bank floor.
// ---------------------------------------------------------------------------
__global__ __launch_bounds__(256) void cvtx_kernel(
    const float* __restrict__ x, unsigned short* __restrict__ xb,
    unsigned short* __restrict__ xT) {
  __shared__ unsigned short T[64 * 64];
  const int tid = threadIdx.x;
  const int d0 = blockIdx.x * 64, l0 = blockIdx.y * 64, b = blockIdx.z;
#pragma unroll
  for (int it = 0; it < 4; it++) {
    int slot = it * 256 + tid;
    int r = slot >> 4, c4 = slot & 15;
    const size_t row = (size_t)(b * LSEQ + l0 + r) * EMBED + d0 + c4 * 4;
    f4 v = *(const f4*)(x + row);
    u16x4 hv = (u16x4){f2bf(v[0]), f2bf(v[1]), f2bf(v[2]), f2bf(v[3])};
    *(u16x4*)(xb + row) = hv;
    const int g = ((r >> 2) ^ c4) << 2;  // swizzled granule base (c4 = d>>2)
#pragma unroll
    for (int j = 0; j < 4; j++)
      T[(c4 * 4 + j) * 64 + g + (r & 3)] = hv[j];
  }
  __syncthreads();
#pragma unroll
  for (int it = 0; it < 2; it++) {
    int slot = it * 256 + tid;
    int dd = slot >> 3, ch = slot & 7;
    int q = dd >> 2;
    u16x4 lo = *(const u16x4*)(T + dd * 64 + (((2 * ch) ^ q) << 2));
    u16x4 hi = *(const u16x4*)(T + dd * 64 + (((2 * ch + 1) ^ q) << 2));
    u16x8 o = (u16x8){lo[0], lo[1], lo[2], lo[3], hi[0], hi[1], hi[2], hi[3]};
    *(u16x8*)(xT + ((size_t)(b * EMBED + d0 + dd)) * LSEQ + l0 + ch * 8) = o;
  }
}

// ---------------------------------------------------------------------------
// cvtw: qw/kw fp32 [k][n] -> wt bf16 [n][k], n in [0,512) = [q | k]
// ---------------------------------------------------------------------------
__global__ __launch_bounds__(256) void cvtw_kernel(
    const float* __restrict__ qw, const float* __restrict__ kw,
    unsigned short* __restrict__ wt) {
  __shared__ unsigned short T[64][72];
  const int tid = threadIdx.x;
  const int n0 = blockIdx.x * 64, k0 = blockIdx.y * 64;
  const float* W = blockIdx.z ? kw : qw;
#pragma unroll
  for (int it = 0; it < 4; it++) {
    int slot = it * 256 + tid;
    int r = slot >> 4, c4 = slot & 15;  // r: k-local, c4: n-chunk
    f4 v = *(const f4*)(W + (size_t)(k0 + r) * PROJ + n0 + c4 * 4);
#pragma unroll
    for (int j = 0; j < 4; j++) T[c4 * 4 + j][r] = f2bf(v[j]);
  }
  __syncthreads();
#pragma unroll
  for (int it = 0; it < 2; it++) {
    int slot = it * 256 + tid;
    int n = slot >> 3, ch = slot & 7;
    *(u16x8*)(wt + ((size_t)(blockIdx.z * PROJ + n0 + n)) * EMBED + k0 + ch * 8) =
        *(const u16x8*)&T[n][ch * 8];
  }
}

// ---------------------------------------------------------------------------
// proj: C[m][n] = exp(xb @ wt^T). M=32768, N=512, K=1024. 128x128 tile, BK=64.
// ---------------------------------------------------------------------------
__global__ __launch_bounds__(256) void proj_kernel(
    const unsigned short* __restrict__ xb, const unsigned short* __restrict__ wt,
    unsigned short* __restrict__ qp, unsigned short* __restrict__ kT) {
  __shared__ union {
    struct { unsigned short A[128 * 64]; unsigned short B[128 * 64]; } t;
    unsigned short T[128 * 136];
  } sm;
  const int tid = threadIdx.x, wave = tid >> 6, lane = tid & 63;
  const int quad = lane >> 4, l16 = lane & 15;
  const int wm = wave >> 1, wn = wave & 1;
  const int n0 = blockIdx.x * 128, m0 = blockIdx.y * 128;

  f4 acc[4][4];
#pragma unroll
  for (int i = 0; i < 4; i++)
#pragma unroll
    for (int j = 0; j < 4; j++) acc[i][j] = (f4){0.f, 0.f, 0.f, 0.f};

  for (int k0 = 0; k0 < EMBED; k0 += 64) {
    stage_tile(xb, m0, EMBED, k0, sm.t.A, wave, lane);
    stage_tile(wt, n0, EMBED, k0, sm.t.B, wave, lane);
    __syncthreads();
#pragma unroll
    for (int ks = 0; ks < 2; ks++) {
      bfrag a[4], bfr[4];
#pragma unroll
      for (int mt = 0; mt < 4; mt++)
        a[mt] = read_frag(sm.t.A, wm * 64 + mt * 16 + l16, ks * 4 + quad);
#pragma unroll
      for (int nt = 0; nt < 4; nt++)
        bfr[nt] = read_frag(sm.t.B, wn * 64 + nt * 16 + l16, ks * 4 + quad);
#pragma unroll
      for (int mt = 0; mt < 4; mt++)
#pragma unroll
        for (int nt = 0; nt < 4; nt++)
          acc[mt][nt] = __builtin_amdgcn_mfma_f32_16x16x32_bf16(
              a[mt], bfr[nt], acc[mt][nt], 0, 0, 0);
    }
    __syncthreads();
  }

  if (n0 < PROJ) {
    // q-half: T[l][e], then coalesced rows into qp[m][e]
#pragma unroll
    for (int mt = 0; mt < 4; mt++)
#pragma unroll
      for (int nt = 0; nt < 4; nt++)
#pragma unroll
        for (int r = 0; r < 4; r++)
          sm.T[(wm * 64 + mt * 16 + quad * 4 + r) * 136 + wn * 64 + nt * 16 + l16] =
              f2bf(__expf(acc[mt][nt][r]));
    __syncthreads();
#pragma unroll
    for (int it = 0; it < 8; it++) {
      int slot = it * 256 + tid;
      int row = slot >> 4, ch = slot & 15;
      *(u16x8*)(qp + (size_t)(m0 + row) * PROJ + n0 + ch * 8) =
          *(const u16x8*)&sm.T[row * 136 + ch * 8];
    }
  } else {
    // k-half: T[e][l], then coalesced rows into kT[b][e][l]
#pragma unroll
    for (int mt = 0; mt < 4; mt++)
#pragma unroll
      for (int nt = 0; nt < 4; nt++) {
        u16x4 h;
#pragma unroll
        for (int r = 0; r < 4; r++) h[r] = f2bf(__expf(acc[mt][nt][r]));
        *(u16x4*)&sm.T[(wn * 64 + nt * 16 + l16) * 136 + wm * 64 + mt * 16 + quad * 4] = h;
      }
    __syncthreads();
    const int bb = m0 >> 12, l0 = m0 & 4095, ebase = n0 - PROJ;
#pragma unroll
    for (int it = 0; it < 8; it++) {
      int slot = it * 256 + tid;
      int e = slot >> 4, ch = slot & 15;
      *(u16x8*)(kT + (size_t)(bb * PROJ + ebase + e) * LSEQ + l0 + ch * 8) =
          *(const u16x8*)&sm.T[e * 136 + ch * 8];
    }
  }
}

// ---------------------------------------------------------------------------
// zinv[m] = 1 / (sum_e qp[m][e] + 1e-8)
// ---------------------------------------------------------------------------
__global__ __launch_bounds__(256) void zinv_kernel(
    const unsigned short* __restrict__ qp, float* __restrict__ zinv) {
  int m = blockIdx.x * 4 + (threadIdx.x >> 6);
  int lane = threadIdx.x & 63;
  u16x4 h = *(const u16x4*)(qp + (size_t)m * PROJ + lane * 4);
  float s = bf2f(h[0]) + bf2f(h[1]) + bf2f(h[2]) + bf2f(h[3]);
#pragma unroll
  for (int off = 32; off; off >>= 1) s += __shfl_xor(s, off);
  if (lane == 0) zinv[m] = 1.0f / (s + 1e-8f);
}

// ---------------------------------------------------------------------------
// kv: kvp[split][b][e][d] = sum_{l in chunk} kT[b][e][l] * xT[b][d][l]
// 128x128 tile, BK=64, K-chunk=1024 (split 4).
// ---------------------------------------------------------------------------
__global__ __launch_bounds__(256) void kv_kernel(
    const unsigned short* __restrict__ kT, const unsigned short* __restrict__ xT,
    float* __restrict__ kvp) {
  __shared__ struct { unsigned short A[128 * 64]; unsigned short B[128 * 64]; } sm;
  const int tid = threadIdx.x, wave = tid >> 6, lane = tid & 63;
  const int quad = lane >> 4, l16 = lane & 15;
  const int wm = wave >> 1, wn = wave & 1;
  const int d0 = blockIdx.x * 128, e0 = blockIdx.y * 128;
  const int b = blockIdx.z & 7, split = blockIdx.z >> 3;
  const unsigned short* As = kT + (size_t)b * PROJ * LSEQ;
  const unsigned short* Bs = xT + (size_t)b * EMBED * LSEQ;

  f4 acc[4][4];
#pragma unroll
  for (int i = 0; i < 4; i++)
#pragma unroll
    for (int j = 0; j < 4; j++) acc[i][j] = (f4){0.f, 0.f, 0.f, 0.f};

  const int kbase = split * 1024;
  for (int kk = 0; kk < 1024; kk += 64) {
    stage_tile(As, e0, LSEQ, kbase + kk, sm.A, wave, lane);
    stage_tile(Bs, d0, LSEQ, kbase + kk, sm.B, wave, lane);
    __syncthreads();
#pragma unroll
    for (int ks = 0; ks < 2; ks++) {
      bfrag a[4], bfr[4];
#pragma unroll
      for (int mt = 0; mt < 4; mt++)
        a[mt] = read_frag(sm.A, wm * 64 + mt * 16 + l16, ks * 4 + quad);
#pragma unroll
      for (int nt = 0; nt < 4; nt++)
        bfr[nt] = read_frag(sm.B, wn * 64 + nt * 16 + l16, ks * 4 + quad);
#pragma unroll
      for (int mt = 0; mt < 4; mt++)
#pragma unroll
        for (int nt = 0; nt < 4; nt++)
          acc[mt][nt] = __builtin_amdgcn_mfma_f32_16x16x32_bf16(
              a[mt], bfr[nt], acc[mt][nt], 0, 0, 0);
    }
    __syncthreads();
  }

#pragma unroll
  for (int mt = 0; mt < 4; mt++)
#pragma unroll
    for (int nt = 0; nt < 4; nt++)
#pragma unroll
      for (int r = 0; r < 4; r++) {
        int e = e0 + wm * 64 + mt * 16 + quad * 4 + r;
        int d = d0 + wn * 64 + nt * 16 + l16;
        kvp[((size_t)(split * 8 + b) * PROJ + e) * EMBED + d] = acc[mt][nt][r];
      }
}

// ---------------------------------------------------------------------------
// kvreduce: kvT[b][d][e] bf16 = f2bf( sum_split kvp[split][b][e][d] )
// ---------------------------------------------------------------------------
__global__ __launch_bounds__(256) void kvreduce_kernel(
    const float* __restrict__ kvp, unsigned short* __restrict__ kvT) {
  __shared__ float T[64][68];
  const int tid = threadIdx.x;
  const int d0 = blockIdx.x * 64, e0 = blockIdx.y * 64, b = blockIdx.z;
#pragma unroll
  for (int it = 0; it < 4; it++) {
    int slot = it * 256 + tid;
    int e = slot >> 4, c4 = slot & 15;
    f4 s = (f4){0.f, 0.f, 0.f, 0.f};
#pragma unroll
    for (int sp = 0; sp < 4; sp++)
      s += *(const f4*)(kvp + ((size_t)(sp * 8 + b) * PROJ + e0 + e) * EMBED + d0 + c4 * 4);
#pragma unroll
    for (int j = 0; j < 4; j++) T[c4 * 4 + j][e] = s[j];
  }
  __syncthreads();
#pragma unroll
  for (int it = 0; it < 2; it++) {
    int slot = it * 256 + tid;
    int d = slot >> 3, ch = slot & 7;
    u16x8 h;
#pragma unroll
    for (int j = 0; j < 8; j++) h[j] = f2bf(T[d][ch * 8 + j]);
    *(u16x8*)(kvT + ((size_t)(b * EMBED + d0 + d)) * PROJ + e0 + ch * 8) = h;
  }
}

// ---------------------------------------------------------------------------
// out: out[b][l][d] = (qp[b][l][:] @ kv[b][:][d]) * zinv[b][l]
// A = qp [l][e], B = kvT [d][e]. 128x128 tile, BK=64, K=256.
// ---------------------------------------------------------------------------
__global__ __launch_bounds__(256) void out_kernel(
    const unsigned short* __restrict__ qp, const unsigned short* __restrict__ kvT,
    const float* __restrict__ zinv, float* __restrict__ out) {
  __shared__ struct { unsigned short A[128 * 64]; unsigned short B[128 * 64]; } sm;
  __shared__ float zv[128];
  const int tid = threadIdx.x, wave = tid >> 6, lane = tid & 63;
  const int quad = lane >> 4, l16 = lane & 15;
  const int wm = wave >> 1, wn = wave & 1;
  const int d0 = blockIdx.x * 128, l0 = blockIdx.y * 128, b = blockIdx.z;
  const unsigned short* As = qp + (size_t)b * LSEQ * PROJ;
  const unsigned short* Bs = kvT + (size_t)b * EMBED * PROJ;

  if (tid < 128) zv[tid] = zinv[b * LSEQ + l0 + tid];

  f4 acc[4][4];
#pragma unroll
  for (int i = 0; i < 4; i++)
#pragma unroll
    for (int j = 0; j < 4; j++) acc[i][j] = (f4){0.f, 0.f, 0.f, 0.f};

  for (int k0 = 0; k0 < PROJ; k0 += 64) {
    stage_tile(As, l0, PROJ, k0, sm.A, wave, lane);
    stage_tile(Bs, d0, PROJ, k0, sm.B, wave, lane);
    __syncthreads();
#pragma unroll
    for (int ks = 0; ks < 2; ks++) {
      bfrag a[4], bfr[4];
#pragma unroll
      for (int mt = 0; mt < 4; mt++)
        a[mt] = read_frag(sm.A, wm * 64 + mt * 16 + l16, ks * 4 + quad);
#pragma unroll
      for (int nt = 0; nt < 4; nt++)
        bfr[nt] = read_frag(sm.B, wn * 64 + nt * 16 + l16, ks * 4 + quad);
#pragma unroll
      for (int mt = 0; mt < 4; mt++)
#pragma unroll
        for (int nt = 0; nt < 4; nt++)
          acc[mt][nt] = __builtin_amdgcn_mfma_f32_16x16x32_bf16(
              a[mt], bfr[nt], acc[mt][nt], 0, 0, 0);
    }
    __syncthreads();
  }

#pragma unroll
  for (int mt = 0; mt < 4; mt++)
#pragma unroll
    for (int nt = 0; nt < 4; nt++)
#pragma unroll
      for (int r = 0; r < 4; r++) {
        int row = wm * 64 + mt * 16 + quad * 4 + r;
        int d = d0 + wn * 64 + nt * 16 + l16;
        out[((size_t)(b * LSEQ + l0 + row)) * EMBED + d] = acc[mt][nt][r] * zv[row];
      }
}

// ---------------------------------------------------------------------------
// Workspace layout (bytes):
//   xb   @ 0          67,108,864   (bf16 [b][l][d]) -- aliased by kvp later
//   xT   @ 67108864   67,108,864   (bf16 [b][d][l])
//   wt   @ 134217728   1,048,576   (bf16 [n][k], n=[q|k])
//   qp   @ 135266304  16,777,216   (bf16 [m][e])
//   kT   @ 152043520  16,777,216   (bf16 [b][e][l])
//   kvT  @ 168820736   4,194,304   (bf16 [b][d][e])
//   zinv @ 173015040     131,072
//   kvp = xb region (33,554,432 = 4 splits * 8 * 256 * 1024 * 4)  [xb dead]
// total ~165 MB
// ---------------------------------------------------------------------------
extern "C" void kernel_launch(void* const* d_in, const int* in_sizes, int n_in,
                              void* d_out, int out_size, void* d_ws, size_t ws_size,
                              hipStream_t stream) {
  const float* x  = (const float*)d_in[0];
  const float* qw = (const float*)d_in[1];
  const float* kw = (const float*)d_in[2];
  float* out = (float*)d_out;

  char* ws = (char*)d_ws;
  unsigned short* xb   = (unsigned short*)(ws);
  unsigned short* xT   = (unsigned short*)(ws + 67108864);
  unsigned short* wt   = (unsigned short*)(ws + 134217728);
  unsigned short* qp   = (unsigned short*)(ws + 135266304);
  unsigned short* kT   = (unsigned short*)(ws + 152043520);
  unsigned short* kvT  = (unsigned short*)(ws + 168820736);
  float*          zinv = (float*)(ws + 173015040);
  float*          kvp  = (float*)(ws);  // aliases xb (dead after proj)

  cvtx_kernel<<<dim3(16, 64, 8), 256, 0, stream>>>(x, xb, xT);
  cvtw_kernel<<<dim3(4, 16, 2), 256, 0, stream>>>(qw, kw, wt);
  proj_kernel<<<dim3(4, 256), 256, 0, stream>>>(xb, wt, qp, kT);
  zinv_kernel<<<dim3(8192), 256, 0, stream>>>(qp, zinv);
  kv_kernel<<<dim3(8, 2, 32), 256, 0, stream>>>(kT, xT, kvp);
  kvreduce_kernel<<<dim3(16, 4, 8), 256, 0, stream>>>(kvp, kvT);
  out_kernel<<<dim3(8, 32, 8), 256, 0, stream>>>(qp, kvT, zinv, out);
}

// Round 3
// 386.420 us; speedup vs baseline: 1.0300x; 1.0060x over previous
//
#include <hip/hip_runtime.h>

// ---------------------------------------------------------------------------
// LinearAttention (FAVOR-style), all GEMMs as bf16 MFMA 16x16x32.
// Intermediates xb/xT/kT are stored in 64x64-TILE-BLOCKED layout (8KB blobs):
// transposes/epilogues write kilobyte-contiguous streams (DRAM-page friendly),
// and stage_tile_blk reads blobs with per-lane addresses via global_load_lds.
//   cvtx:  x fp32 -> xb_blk[mt][dt] bf16  AND  xT_blk[b][dt][lt] bf16
//   cvtw:  qw,kw fp32 -> wt[n][k] bf16 (row-major, tiny)
//   proj:  C = x @ W; q-half -> exp -> qp[m][e] (row-major);
//          k-half -> exp -> kT_blk[b][et][lt]
//   zinv:  1/(rowsum(qp)+1e-8)
//   kv:    kT @ x  (K-split 4, fp32 partials) -> kvreduce -> kvT[b][d][e]
//   out:   (qp @ kv) * zinv
// ---------------------------------------------------------------------------

#define EMBED 1024
#define PROJ  256
#define LSEQ  4096
#define BATCH 8

typedef short  bfrag __attribute__((ext_vector_type(8)));  // 8 bf16 = 1 MFMA frag
typedef float  f4    __attribute__((ext_vector_type(4)));
typedef unsigned short u16x8 __attribute__((ext_vector_type(8)));
typedef unsigned short u16x4 __attribute__((ext_vector_type(4)));

static __device__ __forceinline__ unsigned short f2bf(float f) {
  unsigned int u = __builtin_bit_cast(unsigned int, f);
  u += 0x7fffu + ((u >> 16) & 1u);  // RNE
  return (unsigned short)(u >> 16);
}
static __device__ __forceinline__ float bf2f(unsigned short h) {
  unsigned int u = ((unsigned int)h) << 16;
  return __builtin_bit_cast(float, u);
}

// async global->LDS, 16 B per lane; LDS dest = wave-uniform base + lane*16
static __device__ __forceinline__ void gload_lds16(const void* g, void* l) {
  __builtin_amdgcn_global_load_lds(
      (__attribute__((address_space(1))) void*)(unsigned long long)(g),
      (__attribute__((address_space(3))) void*)(unsigned)(unsigned long long)(l),
      16, 0, 0);
}

// Stage a 128x64 bf16 tile from a ROW-MAJOR source.
static __device__ __forceinline__ void stage_tile(
    const unsigned short* __restrict__ src, int row0, int stride, int k0,
    unsigned short* lds, int wave, int lane) {
#pragma unroll
  for (int j = 0; j < 4; j++) {
    int slot = (wave * 4 + j) * 64 + lane;
    int r = slot >> 3, cp = slot & 7;
    int c = cp ^ (r & 7);
    gload_lds16(src + (size_t)(row0 + r) * stride + k0 + c * 8,
                lds + (wave * 4 + j) * 512);
  }
}

// Stage a 128x64 bf16 tile from a 64x64-TILE-BLOCKED source.
// Blob (tile_row, tile_col) is 4096 shorts contiguous; ntcols = tiles per row.
// row0 and k0 must be 64-aligned.
static __device__ __forceinline__ void stage_tile_blk(
    const unsigned short* __restrict__ src, int row0, int ntcols, int k0,
    unsigned short* lds, int wave, int lane) {
#pragma unroll
  for (int j = 0; j < 4; j++) {
    int slot = (wave * 4 + j) * 64 + lane;
    int r = slot >> 3, cp = slot & 7;
    int c = cp ^ (r & 7);
    const unsigned short* blob =
        src + ((((size_t)(row0 >> 6) + (r >> 6)) * ntcols + (k0 >> 6)) << 12);
    gload_lds16(blob + ((r & 63) << 6) + c * 8, lds + (wave * 4 + j) * 512);
  }
}

// read one 16B MFMA fragment from the swizzled tile
static __device__ __forceinline__ bfrag read_frag(const unsigned short* lds,
                                                  int row, int chunk) {
  return *(const bfrag*)(lds + ((row << 3) + (chunk ^ (row & 7))) * 8);
}

// ---------------------------------------------------------------------------
// cvtx: x fp32 [b][l][d] -> xb_blk[(b*4096+l)/64][d/64] + xT_blk[b][d/64][l/64]
// LDS transpose machinery identical to round-2 (conflict-free); global writes
// are now fully-sequential runs into 8KB blobs.
// ---------------------------------------------------------------------------
__global__ __launch_bounds__(256) void cvtx_kernel(
    const float* __restrict__ x, unsigned short* __restrict__ xb,
    unsigned short* __restrict__ xT) {
  __shared__ unsigned short T[64 * 64];
  const int tid = threadIdx.x;
  const int d0 = blockIdx.x * 64, l0 = blockIdx.y * 64, b = blockIdx.z;
  const int mt = (b * LSEQ + l0) >> 6, dt = d0 >> 6;
  unsigned short* xbB = xb + (((size_t)mt * 16 + dt) << 12);
  unsigned short* xTB = xT + ((((size_t)b * 16 + dt) * 64 + (l0 >> 6)) << 12);
#pragma unroll
  for (int it = 0; it < 4; it++) {
    int slot = it * 256 + tid;
    int r = slot >> 4, c4 = slot & 15;
    f4 v = *(const f4*)(x + (size_t)(b * LSEQ + l0 + r) * EMBED + d0 + c4 * 4);
    u16x4 hv = (u16x4){f2bf(v[0]), f2bf(v[1]), f2bf(v[2]), f2bf(v[3])};
    *(u16x4*)(xbB + r * 64 + c4 * 4) = hv;  // sequential 512B per instr
    const int g = ((r >> 2) ^ c4) << 2;  // swizzled granule base (c4 = d>>2)
#pragma unroll
    for (int j = 0; j < 4; j++)
      T[(c4 * 4 + j) * 64 + g + (r & 3)] = hv[j];
  }
  __syncthreads();
#pragma unroll
  for (int it = 0; it < 2; it++) {
    int slot = it * 256 + tid;
    int dd = slot >> 3, ch = slot & 7;
    int q = dd >> 2;
    u16x4 lo = *(const u16x4*)(T + dd * 64 + (((2 * ch) ^ q) << 2));
    u16x4 hi = *(const u16x4*)(T + dd * 64 + (((2 * ch + 1) ^ q) << 2));
    u16x8 o = (u16x8){lo[0], lo[1], lo[2], lo[3], hi[0], hi[1], hi[2], hi[3]};
    *(u16x8*)(xTB + dd * 64 + ch * 8) = o;  // sequential 1KB per instr
  }
}

// ---------------------------------------------------------------------------
// cvtw: qw/kw fp32 [k][n] -> wt bf16 [n][k], n in [0,512) = [q | k] (row-major)
// ---------------------------------------------------------------------------
__global__ __launch_bounds__(256) void cvtw_kernel(
    const float* __restrict__ qw, const float* __restrict__ kw,
    unsigned short* __restrict__ wt) {
  __shared__ unsigned short T[64][72];
  const int tid = threadIdx.x;
  const int n0 = blockIdx.x * 64, k0 = blockIdx.y * 64;
  const float* W = blockIdx.z ? kw : qw;
#pragma unroll
  for (int it = 0; it < 4; it++) {
    int slot = it * 256 + tid;
    int r = slot >> 4, c4 = slot & 15;  // r: k-local, c4: n-chunk
    f4 v = *(const f4*)(W + (size_t)(k0 + r) * PROJ + n0 + c4 * 4);
#pragma unroll
    for (int j = 0; j < 4; j++) T[c4 * 4 + j][r] = f2bf(v[j]);
  }
  __syncthreads();
#pragma unroll
  for (int it = 0; it < 2; it++) {
    int slot = it * 256 + tid;
    int n = slot >> 3, ch = slot & 7;
    *(u16x8*)(wt + ((size_t)(blockIdx.z * PROJ + n0 + n)) * EMBED + k0 + ch * 8) =
        *(const u16x8*)&T[n][ch * 8];
  }
}

// ---------------------------------------------------------------------------
// proj: C[m][n] = exp(xb @ wt^T). M=32768, N=512, K=1024. 128x128 tile, BK=64.
// A from blocked xb; B from row-major wt. k-half epilogue -> blocked kT.
// ---------------------------------------------------------------------------
__global__ __launch_bounds__(256) void proj_kernel(
    const unsigned short* __restrict__ xb, const unsigned short* __restrict__ wt,
    unsigned short* __restrict__ qp, unsigned short* __restrict__ kT) {
  __shared__ union {
    struct { unsigned short A[128 * 64]; unsigned short B[128 * 64]; } t;
    unsigned short T[128 * 136];
  } sm;
  const int tid = threadIdx.x, wave = tid >> 6, lane = tid & 63;
  const int quad = lane >> 4, l16 = lane & 15;
  const int wm = wave >> 1, wn = wave & 1;
  const int n0 = blockIdx.x * 128, m0 = blockIdx.y * 128;

  f4 acc[4][4];
#pragma unroll
  for (int i = 0; i < 4; i++)
#pragma unroll
    for (int j = 0; j < 4; j++) acc[i][j] = (f4){0.f, 0.f, 0.f, 0.f};

  for (int k0 = 0; k0 < EMBED; k0 += 64) {
    stage_tile_blk(xb, m0, 16, k0, sm.t.A, wave, lane);
    stage_tile(wt, n0, EMBED, k0, sm.t.B, wave, lane);
    __syncthreads();
#pragma unroll
    for (int ks = 0; ks < 2; ks++) {
      bfrag a[4], bfr[4];
#pragma unroll
      for (int mt = 0; mt < 4; mt++)
        a[mt] = read_frag(sm.t.A, wm * 64 + mt * 16 + l16, ks * 4 + quad);
#pragma unroll
      for (int nt = 0; nt < 4; nt++)
        bfr[nt] = read_frag(sm.t.B, wn * 64 + nt * 16 + l16, ks * 4 + quad);
#pragma unroll
      for (int mt = 0; mt < 4; mt++)
#pragma unroll
        for (int nt = 0; nt < 4; nt++)
          acc[mt][nt] = __builtin_amdgcn_mfma_f32_16x16x32_bf16(
              a[mt], bfr[nt], acc[mt][nt], 0, 0, 0);
    }
    __syncthreads();
  }

  if (n0 < PROJ) {
    // q-half: T[l][e], then coalesced rows into qp[m][e]
#pragma unroll
    for (int mt = 0; mt < 4; mt++)
#pragma unroll
      for (int nt = 0; nt < 4; nt++)
#pragma unroll
        for (int r = 0; r < 4; r++)
          sm.T[(wm * 64 + mt * 16 + quad * 4 + r) * 136 + wn * 64 + nt * 16 + l16] =
              f2bf(__expf(acc[mt][nt][r]));
    __syncthreads();
#pragma unroll
    for (int it = 0; it < 8; it++) {
      int slot = it * 256 + tid;
      int row = slot >> 4, ch = slot & 15;
      *(u16x8*)(qp + (size_t)(m0 + row) * PROJ + n0 + ch * 8) =
          *(const u16x8*)&sm.T[row * 136 + ch * 8];
    }
  } else {
    // k-half: T[e][l], then blob-major writes into blocked kT
#pragma unroll
    for (int mt = 0; mt < 4; mt++)
#pragma unroll
      for (int nt = 0; nt < 4; nt++) {
        u16x4 h;
#pragma unroll
        for (int r = 0; r < 4; r++) h[r] = f2bf(__expf(acc[mt][nt][r]));
        *(u16x4*)&sm.T[(wn * 64 + nt * 16 + l16) * 136 + wm * 64 + mt * 16 + quad * 4] = h;
      }
    __syncthreads();
    const int bb = m0 >> 12, l0w = m0 & 4095, ebase = n0 - PROJ;
    // 4 blobs (2 e-tiles x 2 l-tiles); 512 u16x8-chunks per blob, blob-major:
#pragma unroll
    for (int it = 0; it < 8; it++) {
      int cid = it * 256 + tid;
      int blobi = cid >> 9, within = cid & 511;
      int er = within >> 3, ch = within & 7;
      int e = (blobi >> 1) * 64 + er, lc = (blobi & 1) * 8 + ch;
      unsigned short* blob =
          kT + ((((size_t)bb * 4 + ((ebase >> 6) + (blobi >> 1))) * 64 +
                 (l0w >> 6) + (blobi & 1)) << 12);
      *(u16x8*)(blob + (er << 6) + ch * 8) = *(const u16x8*)&sm.T[e * 136 + lc * 8];
    }
  }
}

// ---------------------------------------------------------------------------
// zinv[m] = 1 / (sum_e qp[m][e] + 1e-8)
// ---------------------------------------------------------------------------
__global__ __launch_bounds__(256) void zinv_kernel(
    const unsigned short* __restrict__ qp, float* __restrict__ zinv) {
  int m = blockIdx.x * 4 + (threadIdx.x >> 6);
  int lane = threadIdx.x & 63;
  u16x4 h = *(const u16x4*)(qp + (size_t)m * PROJ + lane * 4);
  float s = bf2f(h[0]) + bf2f(h[1]) + bf2f(h[2]) + bf2f(h[3]);
#pragma unroll
  for (int off = 32; off; off >>= 1) s += __shfl_xor(s, off);
  if (lane == 0) zinv[m] = 1.0f / (s + 1e-8f);
}

// ---------------------------------------------------------------------------
// kv: kvp[split][b][e][d] = sum_{l in chunk} kT[e][l] * xT[d][l]
// 128x128 tile, BK=64, K-chunk=1024 (split 4). A,B from blocked layouts.
// ---------------------------------------------------------------------------
__global__ __launch_bounds__(256) void kv_kernel(
    const unsigned short* __restrict__ kT, const unsigned short* __restrict__ xT,
    float* __restrict__ kvp) {
  __shared__ struct { unsigned short A[128 * 64]; unsigned short B[128 * 64]; } sm;
  const int tid = threadIdx.x, wave = tid >> 6, lane = tid & 63;
  const int quad = lane >> 4, l16 = lane & 15;
  const int wm = wave >> 1, wn = wave & 1;
  const int d0 = blockIdx.x * 128, e0 = blockIdx.y * 128;
  const int b = blockIdx.z & 7, split = blockIdx.z >> 3;
  const unsigned short* As = kT + ((size_t)b * 4 * 64 << 12);   // [et][lt] blobs
  const unsigned short* Bs = xT + ((size_t)b * 16 * 64 << 12);  // [dt][lt] blobs

  f4 acc[4][4];
#pragma unroll
  for (int i = 0; i < 4; i++)
#pragma unroll
    for (int j = 0; j < 4; j++) acc[i][j] = (f4){0.f, 0.f, 0.f, 0.f};

  const int kbase = split * 1024;
  for (int kk = 0; kk < 1024; kk += 64) {
    stage_tile_blk(As, e0, 64, kbase + kk, sm.A, wave, lane);
    stage_tile_blk(Bs, d0, 64, kbase + kk, sm.B, wave, lane);
    __syncthreads();
#pragma unroll
    for (int ks = 0; ks < 2; ks++) {
      bfrag a[4], bfr[4];
#pragma unroll
      for (int mt = 0; mt < 4; mt++)
        a[mt] = read_frag(sm.A, wm * 64 + mt * 16 + l16, ks * 4 + quad);
#pragma unroll
      for (int nt = 0; nt < 4; nt++)
        bfr[nt] = read_frag(sm.B, wn * 64 + nt * 16 + l16, ks * 4 + quad);
#pragma unroll
      for (int mt = 0; mt < 4; mt++)
#pragma unroll
        for (int nt = 0; nt < 4; nt++)
          acc[mt][nt] = __builtin_amdgcn_mfma_f32_16x16x32_bf16(
              a[mt], bfr[nt], acc[mt][nt], 0, 0, 0);
    }
    __syncthreads();
  }

#pragma unroll
  for (int mt = 0; mt < 4; mt++)
#pragma unroll
    for (int nt = 0; nt < 4; nt++)
#pragma unroll
      for (int r = 0; r < 4; r++) {
        int e = e0 + wm * 64 + mt * 16 + quad * 4 + r;
        int d = d0 + wn * 64 + nt * 16 + l16;
        kvp[((size_t)(split * 8 + b) * PROJ + e) * EMBED + d] = acc[mt][nt][r];
      }
}

// ---------------------------------------------------------------------------
// kvreduce: kvT[b][d][e] bf16 = f2bf( sum_split kvp[split][b][e][d] )
// ---------------------------------------------------------------------------
__global__ __launch_bounds__(256) void kvreduce_kernel(
    const float* __restrict__ kvp, unsigned short* __restrict__ kvT) {
  __shared__ float T[64][68];
  const int tid = threadIdx.x;
  const int d0 = blockIdx.x * 64, e0 = blockIdx.y * 64, b = blockIdx.z;
#pragma unroll
  for (int it = 0; it < 4; it++) {
    int slot = it * 256 + tid;
    int e = slot >> 4, c4 = slot & 15;
    f4 s = (f4){0.f, 0.f, 0.f, 0.f};
#pragma unroll
    for (int sp = 0; sp < 4; sp++)
      s += *(const f4*)(kvp + ((size_t)(sp * 8 + b) * PROJ + e0 + e) * EMBED + d0 + c4 * 4);
#pragma unroll
    for (int j = 0; j < 4; j++) T[c4 * 4 + j][e] = s[j];
  }
  __syncthreads();
#pragma unroll
  for (int it = 0; it < 2; it++) {
    int slot = it * 256 + tid;
    int d = slot >> 3, ch = slot & 7;
    u16x8 h;
#pragma unroll
    for (int j = 0; j < 8; j++) h[j] = f2bf(T[d][ch * 8 + j]);
    *(u16x8*)(kvT + ((size_t)(b * EMBED + d0 + d)) * PROJ + e0 + ch * 8) = h;
  }
}

// ---------------------------------------------------------------------------
// out: out[b][l][d] = (qp[b][l][:] @ kv[b][:][d]) * zinv[b][l]
// A = qp [l][e], B = kvT [d][e] (both row-major). 128x128 tile, BK=64, K=256.
// ---------------------------------------------------------------------------
__global__ __launch_bounds__(256) void out_kernel(
    const unsigned short* __restrict__ qp, const unsigned short* __restrict__ kvT,
    const float* __restrict__ zinv, float* __restrict__ out) {
  __shared__ struct { unsigned short A[128 * 64]; unsigned short B[128 * 64]; } sm;
  __shared__ float zv[128];
  const int tid = threadIdx.x, wave = tid >> 6, lane = tid & 63;
  const int quad = lane >> 4, l16 = lane & 15;
  const int wm = wave >> 1, wn = wave & 1;
  const int d0 = blockIdx.x * 128, l0 = blockIdx.y * 128, b = blockIdx.z;
  const unsigned short* As = qp + (size_t)b * LSEQ * PROJ;
  const unsigned short* Bs = kvT + (size_t)b * EMBED * PROJ;

  if (tid < 128) zv[tid] = zinv[b * LSEQ + l0 + tid];

  f4 acc[4][4];
#pragma unroll
  for (int i = 0; i < 4; i++)
#pragma unroll
    for (int j = 0; j < 4; j++) acc[i][j] = (f4){0.f, 0.f, 0.f, 0.f};

  for (int k0 = 0; k0 < PROJ; k0 += 64) {
    stage_tile(As, l0, PROJ, k0, sm.A, wave, lane);
    stage_tile(Bs, d0, PROJ, k0, sm.B, wave, lane);
    __syncthreads();
#pragma unroll
    for (int ks = 0; ks < 2; ks++) {
      bfrag a[4], bfr[4];
#pragma unroll
      for (int mt = 0; mt < 4; mt++)
        a[mt] = read_frag(sm.A, wm * 64 + mt * 16 + l16, ks * 4 + quad);
#pragma unroll
      for (int nt = 0; nt < 4; nt++)
        bfr[nt] = read_frag(sm.B, wn * 64 + nt * 16 + l16, ks * 4 + quad);
#pragma unroll
      for (int mt = 0; mt < 4; mt++)
#pragma unroll
        for (int nt = 0; nt < 4; nt++)
          acc[mt][nt] = __builtin_amdgcn_mfma_f32_16x16x32_bf16(
              a[mt], bfr[nt], acc[mt][nt], 0, 0, 0);
    }
    __syncthreads();
  }

#pragma unroll
  for (int mt = 0; mt < 4; mt++)
#pragma unroll
    for (int nt = 0; nt < 4; nt++)
#pragma unroll
      for (int r = 0; r < 4; r++) {
        int row = wm * 64 + mt * 16 + quad * 4 + r;
        int d = d0 + wn * 64 + nt * 16 + l16;
        out[((size_t)(b * LSEQ + l0 + row)) * EMBED + d] = acc[mt][nt][r] * zv[row];
      }
}

// ---------------------------------------------------------------------------
// Workspace layout (bytes):
//   xb   @ 0          67,108,864   (bf16 blocked [mt][dt][64][64]) -- kvp alias
//   xT   @ 67108864   67,108,864   (bf16 blocked [b][dt][lt][64][64])
//   wt   @ 134217728   1,048,576   (bf16 [n][k], n=[q|k])
//   qp   @ 135266304  16,777,216   (bf16 [m][e])
//   kT   @ 152043520  16,777,216   (bf16 blocked [b][et][lt][64][64])
//   kvT  @ 168820736   4,194,304   (bf16 [b][d][e])
//   zinv @ 173015040     131,072
//   kvp = xb region (33,554,432 = 4 splits * 8 * 256 * 1024 * 4)  [xb dead]
// total ~165 MB
// ---------------------------------------------------------------------------
extern "C" void kernel_launch(void* const* d_in, const int* in_sizes, int n_in,
                              void* d_out, int out_size, void* d_ws, size_t ws_size,
                              hipStream_t stream) {
  const float* x  = (const float*)d_in[0];
  const float* qw = (const float*)d_in[1];
  const float* kw = (const float*)d_in[2];
  float* out = (float*)d_out;

  char* ws = (char*)d_ws;
  unsigned short* xb   = (unsigned short*)(ws);
  unsigned short* xT   = (unsigned short*)(ws + 67108864);
  unsigned short* wt   = (unsigned short*)(ws + 134217728);
  unsigned short* qp   = (unsigned short*)(ws + 135266304);
  unsigned short* kT   = (unsigned short*)(ws + 152043520);
  unsigned short* kvT  = (unsigned short*)(ws + 168820736);
  float*          zinv = (float*)(ws + 173015040);
  float*          kvp  = (float*)(ws);  // aliases xb (dead after proj)

  cvtx_kernel<<<dim3(16, 64, 8), 256, 0, stream>>>(x, xb, xT);
  cvtw_kernel<<<dim3(4, 16, 2), 256, 0, stream>>>(qw, kw, wt);
  proj_kernel<<<dim3(4, 256), 256, 0, stream>>>(xb, wt, qp, kT);
  zinv_kernel<<<dim3(8192), 256, 0, stream>>>(qp, zinv);
  kv_kernel<<<dim3(8, 2, 32), 256, 0, stream>>>(kT, xT, kvp);
  kvreduce_kernel<<<dim3(16, 4, 8), 256, 0, stream>>>(kvp, kvT);
  out_kernel<<<dim3(8, 32, 8), 256, 0, stream>>>(qp, kvT, zinv, out);
}

// Round 4
// 367.846 us; speedup vs baseline: 1.0820x; 1.0505x over previous
//
#include <hip/hip_runtime.h>

// ---------------------------------------------------------------------------
// LinearAttention (FAVOR-style), all GEMMs as bf16 MFMA 16x16x32.
//   cvtb:  x fp32 -> xb bf16 [b][l][d]  (pure streaming convert, no transpose)
//   cvtw:  qw,kw fp32 -> wt[n][k] bf16 (n in [0,512): q cols then k cols)
//   proj:  C = exp(x @ W) (128x128 tile, BK=64, global_load_lds + XOR LDS)
//          q-half -> qp[m][e] row-major; k-half -> kT_blk[b][et][lt] (blocked)
//   zinv:  1/(rowsum(qp)+1e-8)
//   kv:    kT @ x^T with the l<->d transpose done IN LDS (granule-swizzle
//          double pass, verified in cvtx r2/r3), K-split 4, fp32 partials
//   kvreduce -> kvT[b][d][e];  out: (qp @ kv) * zinv
// ---------------------------------------------------------------------------

#define EMBED 1024
#define PROJ  256
#define LSEQ  4096
#define BATCH 8

typedef short  bfrag __attribute__((ext_vector_type(8)));  // 8 bf16 = 1 MFMA frag
typedef float  f4    __attribute__((ext_vector_type(4)));
typedef unsigned short u16x8 __attribute__((ext_vector_type(8)));
typedef unsigned short u16x4 __attribute__((ext_vector_type(4)));

static __device__ __forceinline__ unsigned short f2bf(float f) {
  unsigned int u = __builtin_bit_cast(unsigned int, f);
  u += 0x7fffu + ((u >> 16) & 1u);  // RNE
  return (unsigned short)(u >> 16);
}
static __device__ __forceinline__ float bf2f(unsigned short h) {
  unsigned int u = ((unsigned int)h) << 16;
  return __builtin_bit_cast(float, u);
}

// async global->LDS, 16 B per lane; LDS dest = wave-uniform base + lane*16
static __device__ __forceinline__ void gload_lds16(const void* g, void* l) {
  __builtin_amdgcn_global_load_lds(
      (__attribute__((address_space(1))) void*)(unsigned long long)(g),
      (__attribute__((address_space(3))) void*)(unsigned)(unsigned long long)(l),
      16, 0, 0);
}

// Stage a 128x64 bf16 tile from a ROW-MAJOR source.
static __device__ __forceinline__ void stage_tile(
    const unsigned short* __restrict__ src, int row0, int stride, int k0,
    unsigned short* lds, int wave, int lane) {
#pragma unroll
  for (int j = 0; j < 4; j++) {
    int slot = (wave * 4 + j) * 64 + lane;
    int r = slot >> 3, cp = slot & 7;
    int c = cp ^ (r & 7);
    gload_lds16(src + (size_t)(row0 + r) * stride + k0 + c * 8,
                lds + (wave * 4 + j) * 512);
  }
}

// Stage a 128x64 bf16 tile from a 64x64-TILE-BLOCKED source (8KB blobs).
static __device__ __forceinline__ void stage_tile_blk(
    const unsigned short* __restrict__ src, int row0, int ntcols, int k0,
    unsigned short* lds, int wave, int lane) {
#pragma unroll
  for (int j = 0; j < 4; j++) {
    int slot = (wave * 4 + j) * 64 + lane;
    int r = slot >> 3, cp = slot & 7;
    int c = cp ^ (r & 7);
    const unsigned short* blob =
        src + ((((size_t)(row0 >> 6) + (r >> 6)) * ntcols + (k0 >> 6)) << 12);
    gload_lds16(blob + ((r & 63) << 6) + c * 8, lds + (wave * 4 + j) * 512);
  }
}

// read one 16B MFMA fragment from the XOR-chunk swizzled tile
static __device__ __forceinline__ bfrag read_frag(const unsigned short* lds,
                                                  int row, int chunk) {
  return *(const bfrag*)(lds + ((row << 3) + (chunk ^ (row & 7))) * 8);
}

// ---------------------------------------------------------------------------
// cvtb: pure streaming convert x fp32 -> xb bf16 (row-major, contiguous)
// ---------------------------------------------------------------------------
__global__ __launch_bounds__(256) void cvtb_kernel(
    const float* __restrict__ x, unsigned short* __restrict__ xb) {
  const size_t total = (size_t)BATCH * LSEQ * EMBED;
  size_t i = ((size_t)blockIdx.x * 256 + threadIdx.x) * 8;
  const size_t stride = (size_t)gridDim.x * 256 * 8;
  for (; i < total; i += stride) {
    f4 a = *(const f4*)(x + i);
    f4 b = *(const f4*)(x + i + 4);
    u16x8 h = (u16x8){f2bf(a[0]), f2bf(a[1]), f2bf(a[2]), f2bf(a[3]),
                      f2bf(b[0]), f2bf(b[1]), f2bf(b[2]), f2bf(b[3])};
    *(u16x8*)(xb + i) = h;
  }
}

// ---------------------------------------------------------------------------
// cvtw: qw/kw fp32 [k][n] -> wt bf16 [n][k], n in [0,512) = [q | k] (row-major)
// ---------------------------------------------------------------------------
__global__ __launch_bounds__(256) void cvtw_kernel(
    const float* __restrict__ qw, const float* __restrict__ kw,
    unsigned short* __restrict__ wt) {
  __shared__ unsigned short T[64][72];
  const int tid = threadIdx.x;
  const int n0 = blockIdx.x * 64, k0 = blockIdx.y * 64;
  const float* W = blockIdx.z ? kw : qw;
#pragma unroll
  for (int it = 0; it < 4; it++) {
    int slot = it * 256 + tid;
    int r = slot >> 4, c4 = slot & 15;  // r: k-local, c4: n-chunk
    f4 v = *(const f4*)(W + (size_t)(k0 + r) * PROJ + n0 + c4 * 4);
#pragma unroll
    for (int j = 0; j < 4; j++) T[c4 * 4 + j][r] = f2bf(v[j]);
  }
  __syncthreads();
#pragma unroll
  for (int it = 0; it < 2; it++) {
    int slot = it * 256 + tid;
    int n = slot >> 3, ch = slot & 7;
    *(u16x8*)(wt + ((size_t)(blockIdx.z * PROJ + n0 + n)) * EMBED + k0 + ch * 8) =
        *(const u16x8*)&T[n][ch * 8];
  }
}

// ---------------------------------------------------------------------------
// proj: C[m][n] = exp(xb @ wt^T). M=32768, N=512, K=1024. 128x128 tile, BK=64.
// ---------------------------------------------------------------------------
__global__ __launch_bounds__(256) void proj_kernel(
    const unsigned short* __restrict__ xb, const unsigned short* __restrict__ wt,
    unsigned short* __restrict__ qp, unsigned short* __restrict__ kT) {
  __shared__ union {
    struct { unsigned short A[128 * 64]; unsigned short B[128 * 64]; } t;
    unsigned short T[128 * 136];
  } sm;
  const int tid = threadIdx.x, wave = tid >> 6, lane = tid & 63;
  const int quad = lane >> 4, l16 = lane & 15;
  const int wm = wave >> 1, wn = wave & 1;
  const int n0 = blockIdx.x * 128, m0 = blockIdx.y * 128;

  f4 acc[4][4];
#pragma unroll
  for (int i = 0; i < 4; i++)
#pragma unroll
    for (int j = 0; j < 4; j++) acc[i][j] = (f4){0.f, 0.f, 0.f, 0.f};

  for (int k0 = 0; k0 < EMBED; k0 += 64) {
    stage_tile(xb, m0, EMBED, k0, sm.t.A, wave, lane);
    stage_tile(wt, n0, EMBED, k0, sm.t.B, wave, lane);
    __syncthreads();
#pragma unroll
    for (int ks = 0; ks < 2; ks++) {
      bfrag a[4], bfr[4];
#pragma unroll
      for (int mt = 0; mt < 4; mt++)
        a[mt] = read_frag(sm.t.A, wm * 64 + mt * 16 + l16, ks * 4 + quad);
#pragma unroll
      for (int nt = 0; nt < 4; nt++)
        bfr[nt] = read_frag(sm.t.B, wn * 64 + nt * 16 + l16, ks * 4 + quad);
#pragma unroll
      for (int mt = 0; mt < 4; mt++)
#pragma unroll
        for (int nt = 0; nt < 4; nt++)
          acc[mt][nt] = __builtin_amdgcn_mfma_f32_16x16x32_bf16(
              a[mt], bfr[nt], acc[mt][nt], 0, 0, 0);
    }
    __syncthreads();
  }

  if (n0 < PROJ) {
    // q-half: T[l][e], then coalesced rows into qp[m][e]
#pragma unroll
    for (int mt = 0; mt < 4; mt++)
#pragma unroll
      for (int nt = 0; nt < 4; nt++)
#pragma unroll
        for (int r = 0; r < 4; r++)
          sm.T[(wm * 64 + mt * 16 + quad * 4 + r) * 136 + wn * 64 + nt * 16 + l16] =
              f2bf(__expf(acc[mt][nt][r]));
    __syncthreads();
#pragma unroll
    for (int it = 0; it < 8; it++) {
      int slot = it * 256 + tid;
      int row = slot >> 4, ch = slot & 15;
      *(u16x8*)(qp + (size_t)(m0 + row) * PROJ + n0 + ch * 8) =
          *(const u16x8*)&sm.T[row * 136 + ch * 8];
    }
  } else {
    // k-half: T[e][l], then blob-major writes into blocked kT
#pragma unroll
    for (int mt = 0; mt < 4; mt++)
#pragma unroll
      for (int nt = 0; nt < 4; nt++) {
        u16x4 h;
#pragma unroll
        for (int r = 0; r < 4; r++) h[r] = f2bf(__expf(acc[mt][nt][r]));
        *(u16x4*)&sm.T[(wn * 64 + nt * 16 + l16) * 136 + wm * 64 + mt * 16 + quad * 4] = h;
      }
    __syncthreads();
    const int bb = m0 >> 12, l0w = m0 & 4095, ebase = n0 - PROJ;
#pragma unroll
    for (int it = 0; it < 8; it++) {
      int cid = it * 256 + tid;
      int blobi = cid >> 9, within = cid & 511;
      int er = within >> 3, ch = within & 7;
      int e = (blobi >> 1) * 64 + er, lc = (blobi & 1) * 8 + ch;
      unsigned short* blob =
          kT + ((((size_t)bb * 4 + ((ebase >> 6) + (blobi >> 1))) * 64 +
                 (l0w >> 6) + (blobi & 1)) << 12);
      *(u16x8*)(blob + (er << 6) + ch * 8) = *(const u16x8*)&sm.T[e * 136 + lc * 8];
    }
  }
}

// ---------------------------------------------------------------------------
// zinv[m] = 1 / (sum_e qp[m][e] + 1e-8)
// ---------------------------------------------------------------------------
__global__ __launch_bounds__(256) void zinv_kernel(
    const unsigned short* __restrict__ qp, float* __restrict__ zinv) {
  int m = blockIdx.x * 4 + (threadIdx.x >> 6);
  int lane = threadIdx.x & 63;
  u16x4 h = *(const u16x4*)(qp + (size_t)m * PROJ + lane * 4);
  float s = bf2f(h[0]) + bf2f(h[1]) + bf2f(h[2]) + bf2f(h[3]);
#pragma unroll
  for (int off = 32; off; off >>= 1) s += __shfl_xor(s, off);
  if (lane == 0) zinv[m] = 1.0f / (s + 1e-8f);
}

// ---------------------------------------------------------------------------
// kv: kvp[split][b][e][d] = sum_{l in chunk} kT[e][l] * xb[l][d]
// 128x128 tile, BK=64, K-chunk=1024 (split 4).
// A (kT) staged from blocked layout; B staged RAW [l:64][d:128] from xb and
// transposed in LDS: p1 rows->granule-swizzled T, p2 T->XOR-chunk B-tr
// (overwrites B-raw). All four LDS phases bank-conflict-free (r2-verified
// swizzle arithmetic). Inner MFMA loop unchanged.
// ---------------------------------------------------------------------------
__global__ __launch_bounds__(256) void kv_kernel(
    const unsigned short* __restrict__ kT, const unsigned short* __restrict__ xb,
    float* __restrict__ kvp) {
  __shared__ struct {
    unsigned short A[128 * 64];    // kT tile, XOR-chunk layout
    unsigned short B[128 * 64];    // B-raw [64 l][128 d] -> B-tr [128 d][64 l]
    unsigned short T[2][64 * 64];  // granule-swizzled intermediates
  } sm;
  const int tid = threadIdx.x, wave = tid >> 6, lane = tid & 63;
  const int quad = lane >> 4, l16 = lane & 15;
  const int wm = wave >> 1, wn = wave & 1;
  const int d0 = blockIdx.x * 128, e0 = blockIdx.y * 128;
  const int b = blockIdx.z & 7, split = blockIdx.z >> 3;
  const unsigned short* As = kT + ((size_t)b * 4 * 64 << 12);  // [et][lt] blobs
  const unsigned short* xrow = xb + (size_t)b * LSEQ * EMBED;

  f4 acc[4][4];
#pragma unroll
  for (int i = 0; i < 4; i++)
#pragma unroll
    for (int j = 0; j < 4; j++) acc[i][j] = (f4){0.f, 0.f, 0.f, 0.f};

  const int kbase = split * 1024;
  for (int kk = 0; kk < 1024; kk += 64) {
    stage_tile_blk(As, e0, 64, kbase + kk, sm.A, wave, lane);
    // stage B-raw [l:64][d:128] row-major linear (256B global segments)
#pragma unroll
    for (int j = 0; j < 4; j++) {
      int c = (wave * 4 + j) * 64 + lane;  // chunk 0..1023
      int r = c >> 4, c16 = c & 15;
      gload_lds16(xrow + (size_t)(kbase + kk + r) * EMBED + d0 + c16 * 8,
                  sm.B + (wave * 4 + j) * 512);
    }
    __syncthreads();
    // p1: B-raw rows -> granule-swizzled T (two 64x64 subtiles)
#pragma unroll
    for (int sub = 0; sub < 2; sub++)
#pragma unroll
      for (int it = 0; it < 4; it++) {
        int slot = it * 256 + tid;
        int r = slot >> 4, c4 = slot & 15;  // r: l-row, c4: d-granule
        u16x4 v = *(const u16x4*)(sm.B + r * 128 + sub * 64 + c4 * 4);
        int g = ((r >> 2) ^ c4) << 2;
#pragma unroll
        for (int j2 = 0; j2 < 4; j2++)
          sm.T[sub][(c4 * 4 + j2) * 64 + g + (r & 3)] = v[j2];
      }
    __syncthreads();
    // p2: T -> B-tr [d:128][8 chunks, pos = ch^(d&7)] (overwrites sm.B)
#pragma unroll
    for (int it = 0; it < 4; it++) {
      int slot = it * 256 + tid;
      int d = slot >> 3, ch = slot & 7;
      int sub = d >> 6, dl = d & 63, q = dl >> 2;
      u16x4 lo = *(const u16x4*)(sm.T[sub] + dl * 64 + (((2 * ch) ^ q) << 2));
      u16x4 hi = *(const u16x4*)(sm.T[sub] + dl * 64 + (((2 * ch + 1) ^ q) << 2));
      u16x8 o = (u16x8){lo[0], lo[1], lo[2], lo[3], hi[0], hi[1], hi[2], hi[3]};
      *(u16x8*)(sm.B + d * 64 + (ch ^ (d & 7)) * 8) = o;
    }
    __syncthreads();
#pragma unroll
    for (int ks = 0; ks < 2; ks++) {
      bfrag a[4], bfr[4];
#pragma unroll
      for (int mt = 0; mt < 4; mt++)
        a[mt] = read_frag(sm.A, wm * 64 + mt * 16 + l16, ks * 4 + quad);
#pragma unroll
      for (int nt = 0; nt < 4; nt++)
        bfr[nt] = read_frag(sm.B, wn * 64 + nt * 16 + l16, ks * 4 + quad);
#pragma unroll
      for (int mt = 0; mt < 4; mt++)
#pragma unroll
        for (int nt = 0; nt < 4; nt++)
          acc[mt][nt] = __builtin_amdgcn_mfma_f32_16x16x32_bf16(
              a[mt], bfr[nt], acc[mt][nt], 0, 0, 0);
    }
    __syncthreads();
  }

#pragma unroll
  for (int mt = 0; mt < 4; mt++)
#pragma unroll
    for (int nt = 0; nt < 4; nt++)
#pragma unroll
      for (int r = 0; r < 4; r++) {
        int e = e0 + wm * 64 + mt * 16 + quad * 4 + r;
        int d = d0 + wn * 64 + nt * 16 + l16;
        kvp[((size_t)(split * 8 + b) * PROJ + e) * EMBED + d] = acc[mt][nt][r];
      }
}

// ---------------------------------------------------------------------------
// kvreduce: kvT[b][d][e] bf16 = f2bf( sum_split kvp[split][b][e][d] )
// ---------------------------------------------------------------------------
__global__ __launch_bounds__(256) void kvreduce_kernel(
    const float* __restrict__ kvp, unsigned short* __restrict__ kvT) {
  __shared__ float T[64][68];
  const int tid = threadIdx.x;
  const int d0 = blockIdx.x * 64, e0 = blockIdx.y * 64, b = blockIdx.z;
#pragma unroll
  for (int it = 0; it < 4; it++) {
    int slot = it * 256 + tid;
    int e = slot >> 4, c4 = slot & 15;
    f4 s = (f4){0.f, 0.f, 0.f, 0.f};
#pragma unroll
    for (int sp = 0; sp < 4; sp++)
      s += *(const f4*)(kvp + ((size_t)(sp * 8 + b) * PROJ + e0 + e) * EMBED + d0 + c4 * 4);
#pragma unroll
    for (int j = 0; j < 4; j++) T[c4 * 4 + j][e] = s[j];
  }
  __syncthreads();
#pragma unroll
  for (int it = 0; it < 2; it++) {
    int slot = it * 256 + tid;
    int d = slot >> 3, ch = slot & 7;
    u16x8 h;
#pragma unroll
    for (int j = 0; j < 8; j++) h[j] = f2bf(T[d][ch * 8 + j]);
    *(u16x8*)(kvT + ((size_t)(b * EMBED + d0 + d)) * PROJ + e0 + ch * 8) = h;
  }
}

// ---------------------------------------------------------------------------
// out: out[b][l][d] = (qp[b][l][:] @ kv[b][:][d]) * zinv[b][l]
// A = qp [l][e], B = kvT [d][e] (both row-major). 128x128 tile, BK=64, K=256.
// ---------------------------------------------------------------------------
__global__ __launch_bounds__(256) void out_kernel(
    const unsigned short* __restrict__ qp, const unsigned short* __restrict__ kvT,
    const float* __restrict__ zinv, float* __restrict__ out) {
  __shared__ struct { unsigned short A[128 * 64]; unsigned short B[128 * 64]; } sm;
  __shared__ float zv[128];
  const int tid = threadIdx.x, wave = tid >> 6, lane = tid & 63;
  const int quad = lane >> 4, l16 = lane & 15;
  const int wm = wave >> 1, wn = wave & 1;
  const int d0 = blockIdx.x * 128, l0 = blockIdx.y * 128, b = blockIdx.z;
  const unsigned short* As = qp + (size_t)b * LSEQ * PROJ;
  const unsigned short* Bs = kvT + (size_t)b * EMBED * PROJ;

  if (tid < 128) zv[tid] = zinv[b * LSEQ + l0 + tid];

  f4 acc[4][4];
#pragma unroll
  for (int i = 0; i < 4; i++)
#pragma unroll
    for (int j = 0; j < 4; j++) acc[i][j] = (f4){0.f, 0.f, 0.f, 0.f};

  for (int k0 = 0; k0 < PROJ; k0 += 64) {
    stage_tile(As, l0, PROJ, k0, sm.A, wave, lane);
    stage_tile(Bs, d0, PROJ, k0, sm.B, wave, lane);
    __syncthreads();
#pragma unroll
    for (int ks = 0; ks < 2; ks++) {
      bfrag a[4], bfr[4];
#pragma unroll
      for (int mt = 0; mt < 4; mt++)
        a[mt] = read_frag(sm.A, wm * 64 + mt * 16 + l16, ks * 4 + quad);
#pragma unroll
      for (int nt = 0; nt < 4; nt++)
        bfr[nt] = read_frag(sm.B, wn * 64 + nt * 16 + l16, ks * 4 + quad);
#pragma unroll
      for (int mt = 0; mt < 4; mt++)
#pragma unroll
        for (int nt = 0; nt < 4; nt++)
          acc[mt][nt] = __builtin_amdgcn_mfma_f32_16x16x32_bf16(
              a[mt], bfr[nt], acc[mt][nt], 0, 0, 0);
    }
    __syncthreads();
  }

#pragma unroll
  for (int mt = 0; mt < 4; mt++)
#pragma unroll
    for (int nt = 0; nt < 4; nt++)
#pragma unroll
      for (int r = 0; r < 4; r++) {
        int row = wm * 64 + mt * 16 + quad * 4 + r;
        int d = d0 + wn * 64 + nt * 16 + l16;
        out[((size_t)(b * LSEQ + l0 + row)) * EMBED + d] = acc[mt][nt][r] * zv[row];
      }
}

// ---------------------------------------------------------------------------
// Workspace layout (bytes):
//   xb   @ 0          67,108,864   (bf16 [b][l][d], row-major; alive thru kv)
//   kvp  @ 67108864   33,554,432   (fp32, 4 splits * 8 * 256 * 1024 * 4)
//   wt   @ 134217728   1,048,576   (bf16 [n][k], n=[q|k])
//   qp   @ 135266304  16,777,216   (bf16 [m][e])
//   kT   @ 152043520  16,777,216   (bf16 blocked [b][et][lt][64][64])
//   kvT  @ 168820736   4,194,304   (bf16 [b][d][e])
//   zinv @ 173015040     131,072
// total ~165 MB
// ---------------------------------------------------------------------------
extern "C" void kernel_launch(void* const* d_in, const int* in_sizes, int n_in,
                              void* d_out, int out_size, void* d_ws, size_t ws_size,
                              hipStream_t stream) {
  const float* x  = (const float*)d_in[0];
  const float* qw = (const float*)d_in[1];
  const float* kw = (const float*)d_in[2];
  float* out = (float*)d_out;

  char* ws = (char*)d_ws;
  unsigned short* xb   = (unsigned short*)(ws);
  float*          kvp  = (float*)(ws + 67108864);
  unsigned short* wt   = (unsigned short*)(ws + 134217728);
  unsigned short* qp   = (unsigned short*)(ws + 135266304);
  unsigned short* kT   = (unsigned short*)(ws + 152043520);
  unsigned short* kvT  = (unsigned short*)(ws + 168820736);
  float*          zinv = (float*)(ws + 173015040);

  cvtb_kernel<<<dim3(2048), 256, 0, stream>>>(x, xb);
  cvtw_kernel<<<dim3(4, 16, 2), 256, 0, stream>>>(qw, kw, wt);
  proj_kernel<<<dim3(4, 256), 256, 0, stream>>>(xb, wt, qp, kT);
  zinv_kernel<<<dim3(8192), 256, 0, stream>>>(qp, zinv);
  kv_kernel<<<dim3(8, 2, 32), 256, 0, stream>>>(kT, xb, kvp);
  kvreduce_kernel<<<dim3(16, 4, 8), 256, 0, stream>>>(kvp, kvT);
  out_kernel<<<dim3(8, 32, 8), 256, 0, stream>>>(qp, kvT, zinv, out);
}

// Round 5
// 364.415 us; speedup vs baseline: 1.0922x; 1.0094x over previous
//
#include <hip/hip_runtime.h>

// ---------------------------------------------------------------------------
// LinearAttention (FAVOR-style), all GEMMs as bf16 MFMA 16x16x32.
//   cvtb:  x fp32 -> xb bf16 [b][l][d]  (pure streaming convert, no transpose)
//   cvtw:  qw,kw fp32 -> wt[n][k] bf16 (n in [0,512): q cols then k cols)
//   proj:  C = exp(x @ W) (128x128 tile, BK=64, global_load_lds + XOR LDS)
//          q-half -> qp[m][e] row-major; k-half -> kT_blk[b][et][lt] (blocked)
//   zinv:  1/(rowsum(qp)+1e-8)
//   kv:    kT @ x^T, K-split 4. B (x) transposed per K-step via REGISTER 4x8
//          transpose (src-pre-swizzled staging, bank-floor LDS), double-
//          buffered staging with counted vmcnt(8) + raw barriers (T3min+T4).
//   kvreduce -> kvT[b][d][e];  out: (qp @ kv) * zinv
// ---------------------------------------------------------------------------

#define EMBED 1024
#define PROJ  256
#define LSEQ  4096
#define BATCH 8

typedef short  bfrag __attribute__((ext_vector_type(8)));  // 8 bf16 = 1 MFMA frag
typedef float  f4    __attribute__((ext_vector_type(4)));
typedef unsigned short u16x8 __attribute__((ext_vector_type(8)));
typedef unsigned short u16x4 __attribute__((ext_vector_type(4)));

static __device__ __forceinline__ unsigned short f2bf(float f) {
  unsigned int u = __builtin_bit_cast(unsigned int, f);
  u += 0x7fffu + ((u >> 16) & 1u);  // RNE
  return (unsigned short)(u >> 16);
}
static __device__ __forceinline__ float bf2f(unsigned short h) {
  unsigned int u = ((unsigned int)h) << 16;
  return __builtin_bit_cast(float, u);
}

// async global->LDS, 16 B per lane; LDS dest = wave-uniform base + lane*16
static __device__ __forceinline__ void gload_lds16(const void* g, void* l) {
  __builtin_amdgcn_global_load_lds(
      (__attribute__((address_space(1))) void*)(unsigned long long)(g),
      (__attribute__((address_space(3))) void*)(unsigned)(unsigned long long)(l),
      16, 0, 0);
}

// Stage a 128x64 bf16 tile from a ROW-MAJOR source.
static __device__ __forceinline__ void stage_tile(
    const unsigned short* __restrict__ src, int row0, int stride, int k0,
    unsigned short* lds, int wave, int lane) {
#pragma unroll
  for (int j = 0; j < 4; j++) {
    int slot = (wave * 4 + j) * 64 + lane;
    int r = slot >> 3, cp = slot & 7;
    int c = cp ^ (r & 7);
    gload_lds16(src + (size_t)(row0 + r) * stride + k0 + c * 8,
                lds + (wave * 4 + j) * 512);
  }
}

// Stage a 128x64 bf16 tile from a 64x64-TILE-BLOCKED source (8KB blobs).
static __device__ __forceinline__ void stage_tile_blk(
    const unsigned short* __restrict__ src, int row0, int ntcols, int k0,
    unsigned short* lds, int wave, int lane) {
#pragma unroll
  for (int j = 0; j < 4; j++) {
    int slot = (wave * 4 + j) * 64 + lane;
    int r = slot >> 3, cp = slot & 7;
    int c = cp ^ (r & 7);
    const unsigned short* blob =
        src + ((((size_t)(row0 >> 6) + (r >> 6)) * ntcols + (k0 >> 6)) << 12);
    gload_lds16(blob + ((r & 63) << 6) + c * 8, lds + (wave * 4 + j) * 512);
  }
}

// read one 16B MFMA fragment from the XOR-chunk swizzled tile
static __device__ __forceinline__ bfrag read_frag(const unsigned short* lds,
                                                  int row, int chunk) {
  return *(const bfrag*)(lds + ((row << 3) + (chunk ^ (row & 7))) * 8);
}

// ---------------------------------------------------------------------------
// cvtb: pure streaming convert x fp32 -> xb bf16 (row-major, contiguous)
// ---------------------------------------------------------------------------
__global__ __launch_bounds__(256) void cvtb_kernel(
    const float* __restrict__ x, unsigned short* __restrict__ xb) {
  const size_t total = (size_t)BATCH * LSEQ * EMBED;
  size_t i = ((size_t)blockIdx.x * 256 + threadIdx.x) * 8;
  const size_t stride = (size_t)gridDim.x * 256 * 8;
  for (; i < total; i += stride) {
    f4 a = *(const f4*)(x + i);
    f4 b = *(const f4*)(x + i + 4);
    u16x8 h = (u16x8){f2bf(a[0]), f2bf(a[1]), f2bf(a[2]), f2bf(a[3]),
                      f2bf(b[0]), f2bf(b[1]), f2bf(b[2]), f2bf(b[3])};
    *(u16x8*)(xb + i) = h;
  }
}

// ---------------------------------------------------------------------------
// cvtw: qw/kw fp32 [k][n] -> wt bf16 [n][k], n in [0,512) = [q | k] (row-major)
// ---------------------------------------------------------------------------
__global__ __launch_bounds__(256) void cvtw_kernel(
    const float* __restrict__ qw, const float* __restrict__ kw,
    unsigned short* __restrict__ wt) {
  __shared__ unsigned short T[64][72];
  const int tid = threadIdx.x;
  const int n0 = blockIdx.x * 64, k0 = blockIdx.y * 64;
  const float* W = blockIdx.z ? kw : qw;
#pragma unroll
  for (int it = 0; it < 4; it++) {
    int slot = it * 256 + tid;
    int r = slot >> 4, c4 = slot & 15;  // r: k-local, c4: n-chunk
    f4 v = *(const f4*)(W + (size_t)(k0 + r) * PROJ + n0 + c4 * 4);
#pragma unroll
    for (int j = 0; j < 4; j++) T[c4 * 4 + j][r] = f2bf(v[j]);
  }
  __syncthreads();
#pragma unroll
  for (int it = 0; it < 2; it++) {
    int slot = it * 256 + tid;
    int n = slot >> 3, ch = slot & 7;
    *(u16x8*)(wt + ((size_t)(blockIdx.z * PROJ + n0 + n)) * EMBED + k0 + ch * 8) =
        *(const u16x8*)&T[n][ch * 8];
  }
}

// ---------------------------------------------------------------------------
// proj: C[m][n] = exp(xb @ wt^T). M=32768, N=512, K=1024. 128x128 tile, BK=64.
// ---------------------------------------------------------------------------
__global__ __launch_bounds__(256) void proj_kernel(
    const unsigned short* __restrict__ xb, const unsigned short* __restrict__ wt,
    unsigned short* __restrict__ qp, unsigned short* __restrict__ kT) {
  __shared__ union {
    struct { unsigned short A[128 * 64]; unsigned short B[128 * 64]; } t;
    unsigned short T[128 * 136];
  } sm;
  const int tid = threadIdx.x, wave = tid >> 6, lane = tid & 63;
  const int quad = lane >> 4, l16 = lane & 15;
  const int wm = wave >> 1, wn = wave & 1;
  const int n0 = blockIdx.x * 128, m0 = blockIdx.y * 128;

  f4 acc[4][4];
#pragma unroll
  for (int i = 0; i < 4; i++)
#pragma unroll
    for (int j = 0; j < 4; j++) acc[i][j] = (f4){0.f, 0.f, 0.f, 0.f};

  for (int k0 = 0; k0 < EMBED; k0 += 64) {
    stage_tile(xb, m0, EMBED, k0, sm.t.A, wave, lane);
    stage_tile(wt, n0, EMBED, k0, sm.t.B, wave, lane);
    __syncthreads();
#pragma unroll
    for (int ks = 0; ks < 2; ks++) {
      bfrag a[4], bfr[4];
#pragma unroll
      for (int mt = 0; mt < 4; mt++)
        a[mt] = read_frag(sm.t.A, wm * 64 + mt * 16 + l16, ks * 4 + quad);
#pragma unroll
      for (int nt = 0; nt < 4; nt++)
        bfr[nt] = read_frag(sm.t.B, wn * 64 + nt * 16 + l16, ks * 4 + quad);
#pragma unroll
      for (int mt = 0; mt < 4; mt++)
#pragma unroll
        for (int nt = 0; nt < 4; nt++)
          acc[mt][nt] = __builtin_amdgcn_mfma_f32_16x16x32_bf16(
              a[mt], bfr[nt], acc[mt][nt], 0, 0, 0);
    }
    __syncthreads();
  }

  if (n0 < PROJ) {
    // q-half: T[l][e], then coalesced rows into qp[m][e]
#pragma unroll
    for (int mt = 0; mt < 4; mt++)
#pragma unroll
      for (int nt = 0; nt < 4; nt++)
#pragma unroll
        for (int r = 0; r < 4; r++)
          sm.T[(wm * 64 + mt * 16 + quad * 4 + r) * 136 + wn * 64 + nt * 16 + l16] =
              f2bf(__expf(acc[mt][nt][r]));
    __syncthreads();
#pragma unroll
    for (int it = 0; it < 8; it++) {
      int slot = it * 256 + tid;
      int row = slot >> 4, ch = slot & 15;
      *(u16x8*)(qp + (size_t)(m0 + row) * PROJ + n0 + ch * 8) =
          *(const u16x8*)&sm.T[row * 136 + ch * 8];
    }
  } else {
    // k-half: T[e][l], then blob-major writes into blocked kT
#pragma unroll
    for (int mt = 0; mt < 4; mt++)
#pragma unroll
      for (int nt = 0; nt < 4; nt++) {
        u16x4 h;
#pragma unroll
        for (int r = 0; r < 4; r++) h[r] = f2bf(__expf(acc[mt][nt][r]));
        *(u16x4*)&sm.T[(wn * 64 + nt * 16 + l16) * 136 + wm * 64 + mt * 16 + quad * 4] = h;
      }
    __syncthreads();
    const int bb = m0 >> 12, l0w = m0 & 4095, ebase = n0 - PROJ;
#pragma unroll
    for (int it = 0; it < 8; it++) {
      int cid = it * 256 + tid;
      int blobi = cid >> 9, within = cid & 511;
      int er = within >> 3, ch = within & 7;
      int e = (blobi >> 1) * 64 + er, lc = (blobi & 1) * 8 + ch;
      unsigned short* blob =
          kT + ((((size_t)bb * 4 + ((ebase >> 6) + (blobi >> 1))) * 64 +
                 (l0w >> 6) + (blobi & 1)) << 12);
      *(u16x8*)(blob + (er << 6) + ch * 8) = *(const u16x8*)&sm.T[e * 136 + lc * 8];
    }
  }
}

// ---------------------------------------------------------------------------
// zinv[m] = 1 / (sum_e qp[m][e] + 1e-8)
// ---------------------------------------------------------------------------
__global__ __launch_bounds__(256) void zinv_kernel(
    const unsigned short* __restrict__ qp, float* __restrict__ zinv) {
  int m = blockIdx.x * 4 + (threadIdx.x >> 6);
  int lane = threadIdx.x & 63;
  u16x4 h = *(const u16x4*)(qp + (size_t)m * PROJ + lane * 4);
  float s = bf2f(h[0]) + bf2f(h[1]) + bf2f(h[2]) + bf2f(h[3]);
#pragma unroll
  for (int off = 32; off; off >>= 1) s += __shfl_xor(s, off);
  if (lane == 0) zinv[m] = 1.0f / (s + 1e-8f);
}

// ---------------------------------------------------------------------------
// kv: kvp[split][b][e][d] = sum_{l in chunk} kT[e][l] * xb[l][d]
// 128x128 tile, BK=64, K-chunk=1024 (split 4).
// A (kT) staged from blocked layout (double-buffered).
// B (xb) staged RAW [64 l][128 d] with SOURCE-pre-swizzled chunks
// (Braw[r][c] holds global chunk c ^ ((r>>2)&7); coalescing preserved since
// the permutation stays within each row's 256B segment), double-buffered.
// Per K-step a REGISTER 4lx8d transpose moves Braw -> Btr (XOR-chunk layout
// read_frag expects): 4x ds_read_b128 + 8x ds_write_b64 per thread, both at
// the bank floor by construction. Loop uses counted vmcnt(8) + raw barriers
// so next-tile staging stays in flight across barriers (T3min+T4).
// ---------------------------------------------------------------------------
__global__ __launch_bounds__(256) void kv_kernel(
    const unsigned short* __restrict__ kT, const unsigned short* __restrict__ xb,
    float* __restrict__ kvp) {
  __shared__ unsigned short sA[2 * 128 * 64];    // kT tiles, XOR-chunk layout
  __shared__ unsigned short sBraw[2 * 64 * 128]; // raw x tiles (src-swizzled)
  __shared__ unsigned short sBtr[128 * 64];      // transposed B, XOR-chunk
  const int tid = threadIdx.x, wave = tid >> 6, lane = tid & 63;
  const int quad = lane >> 4, l16 = lane & 15;
  const int wm = wave >> 1, wn = wave & 1;
  const int d0 = blockIdx.x * 128, e0 = blockIdx.y * 128;
  const int b = blockIdx.z & 7, split = blockIdx.z >> 3;
  const unsigned short* As = kT + ((size_t)b * 4 * 64 << 12);  // [et][lt] blobs
  const unsigned short* xrow = xb + (size_t)b * LSEQ * EMBED;

  f4 acc[4][4];
#pragma unroll
  for (int i = 0; i < 4; i++)
#pragma unroll
    for (int j = 0; j < 4; j++) acc[i][j] = (f4){0.f, 0.f, 0.f, 0.f};

  const int kbase = split * 1024;

  // B-raw staging with source chunk pre-swizzle c16 ^ ((r>>2)&7)
#define STAGE_BRAW(K0, DST)                                                   \
  {                                                                           \
    _Pragma("unroll") for (int j = 0; j < 4; j++) {                           \
      int slot = (wave * 4 + j) * 64 + lane;                                  \
      int r = slot >> 4, c16 = slot & 15;                                     \
      int cg = c16 ^ ((r >> 2) & 7);                                          \
      gload_lds16(xrow + (size_t)((K0) + r) * EMBED + d0 + cg * 8,            \
                  (DST) + (wave * 4 + j) * 512);                              \
    }                                                                         \
  }

  // prologue: stage tile 0 into buffer 0
  stage_tile_blk(As, e0, 64, kbase, sA, wave, lane);
  STAGE_BRAW(kbase, sBraw);

  for (int t = 0; t < 16; ++t) {
    unsigned short* Acur = sA + (t & 1) * 8192;
    const unsigned short* Bcur = sBraw + (t & 1) * 8192;
    if (t < 15) {
      stage_tile_blk(As, e0, 64, kbase + (t + 1) * 64, sA + ((t + 1) & 1) * 8192,
                     wave, lane);
      STAGE_BRAW(kbase + (t + 1) * 64, sBraw + ((t + 1) & 1) * 8192);
      asm volatile("s_waitcnt vmcnt(8)" ::: "memory");  // tile-t loads done
    } else {
      asm volatile("s_waitcnt vmcnt(0)" ::: "memory");
    }
    __builtin_amdgcn_s_barrier();
    __builtin_amdgcn_sched_barrier(0);

    // register 4l x 8d transpose: Bcur -> sBtr
    {
      const int gl = tid & 15, cd = tid >> 4;      // l-group, d-chunk
      const int c = cd ^ (gl & 7);                 // stored chunk of global cd
      const unsigned short* src = Bcur + gl * 512 + c * 8;
      u16x8 i0 = *(const u16x8*)(src);
      u16x8 i1 = *(const u16x8*)(src + 128);
      u16x8 i2 = *(const u16x8*)(src + 256);
      u16x8 i3 = *(const u16x8*)(src + 384);
#pragma unroll
      for (int k = 0; k < 8; k++) {
        int d = cd * 8 + k;
        u16x4 o = (u16x4){i0[k], i1[k], i2[k], i3[k]};
        *(u16x4*)(sBtr + d * 64 + (((gl >> 1) ^ (d & 7)) << 3) + ((gl & 1) << 2)) = o;
      }
    }
    asm volatile("s_waitcnt lgkmcnt(0)" ::: "memory");  // Btr writes committed
    __builtin_amdgcn_s_barrier();
    __builtin_amdgcn_sched_barrier(0);

#pragma unroll
    for (int ks = 0; ks < 2; ks++) {
      bfrag a[4], bfr[4];
#pragma unroll
      for (int mt = 0; mt < 4; mt++)
        a[mt] = read_frag(Acur, wm * 64 + mt * 16 + l16, ks * 4 + quad);
#pragma unroll
      for (int nt = 0; nt < 4; nt++)
        bfr[nt] = read_frag(sBtr, wn * 64 + nt * 16 + l16, ks * 4 + quad);
#pragma unroll
      for (int mt = 0; mt < 4; mt++)
#pragma unroll
        for (int nt = 0; nt < 4; nt++)
          acc[mt][nt] = __builtin_amdgcn_mfma_f32_16x16x32_bf16(
              a[mt], bfr[nt], acc[mt][nt], 0, 0, 0);
    }
    __builtin_amdgcn_s_barrier();  // all reads of Acur/Bcur/Btr complete
    __builtin_amdgcn_sched_barrier(0);
  }
#undef STAGE_BRAW

#pragma unroll
  for (int mt = 0; mt < 4; mt++)
#pragma unroll
    for (int nt = 0; nt < 4; nt++)
#pragma unroll
      for (int r = 0; r < 4; r++) {
        int e = e0 + wm * 64 + mt * 16 + quad * 4 + r;
        int d = d0 + wn * 64 + nt * 16 + l16;
        kvp[((size_t)(split * 8 + b) * PROJ + e) * EMBED + d] = acc[mt][nt][r];
      }
}

// ---------------------------------------------------------------------------
// kvreduce: kvT[b][d][e] bf16 = f2bf( sum_split kvp[split][b][e][d] )
// ---------------------------------------------------------------------------
__global__ __launch_bounds__(256) void kvreduce_kernel(
    const float* __restrict__ kvp, unsigned short* __restrict__ kvT) {
  __shared__ float T[64][68];
  const int tid = threadIdx.x;
  const int d0 = blockIdx.x * 64, e0 = blockIdx.y * 64, b = blockIdx.z;
#pragma unroll
  for (int it = 0; it < 4; it++) {
    int slot = it * 256 + tid;
    int e = slot >> 4, c4 = slot & 15;
    f4 s = (f4){0.f, 0.f, 0.f, 0.f};
#pragma unroll
    for (int sp = 0; sp < 4; sp++)
      s += *(const f4*)(kvp + ((size_t)(sp * 8 + b) * PROJ + e0 + e) * EMBED + d0 + c4 * 4);
#pragma unroll
    for (int j = 0; j < 4; j++) T[c4 * 4 + j][e] = s[j];
  }
  __syncthreads();
#pragma unroll
  for (int it = 0; it < 2; it++) {
    int slot = it * 256 + tid;
    int d = slot >> 3, ch = slot & 7;
    u16x8 h;
#pragma unroll
    for (int j = 0; j < 8; j++) h[j] = f2bf(T[d][ch * 8 + j]);
    *(u16x8*)(kvT + ((size_t)(b * EMBED + d0 + d)) * PROJ + e0 + ch * 8) = h;
  }
}

// ---------------------------------------------------------------------------
// out: out[b][l][d] = (qp[b][l][:] @ kv[b][:][d]) * zinv[b][l]
// A = qp [l][e], B = kvT [d][e] (both row-major). 128x128 tile, BK=64, K=256.
// ---------------------------------------------------------------------------
__global__ __launch_bounds__(256) void out_kernel(
    const unsigned short* __restrict__ qp, const unsigned short* __restrict__ kvT,
    const float* __restrict__ zinv, float* __restrict__ out) {
  __shared__ struct { unsigned short A[128 * 64]; unsigned short B[128 * 64]; } sm;
  __shared__ float zv[128];
  const int tid = threadIdx.x, wave = tid >> 6, lane = tid & 63;
  const int quad = lane >> 4, l16 = lane & 15;
  const int wm = wave >> 1, wn = wave & 1;
  const int d0 = blockIdx.x * 128, l0 = blockIdx.y * 128, b = blockIdx.z;
  const unsigned short* As = qp + (size_t)b * LSEQ * PROJ;
  const unsigned short* Bs = kvT + (size_t)b * EMBED * PROJ;

  if (tid < 128) zv[tid] = zinv[b * LSEQ + l0 + tid];

  f4 acc[4][4];
#pragma unroll
  for (int i = 0; i < 4; i++)
#pragma unroll
    for (int j = 0; j < 4; j++) acc[i][j] = (f4){0.f, 0.f, 0.f, 0.f};

  for (int k0 = 0; k0 < PROJ; k0 += 64) {
    stage_tile(As, l0, PROJ, k0, sm.A, wave, lane);
    stage_tile(Bs, d0, PROJ, k0, sm.B, wave, lane);
    __syncthreads();
#pragma unroll
    for (int ks = 0; ks < 2; ks++) {
      bfrag a[4], bfr[4];
#pragma unroll
      for (int mt = 0; mt < 4; mt++)
        a[mt] = read_frag(sm.A, wm * 64 + mt * 16 + l16, ks * 4 + quad);
#pragma unroll
      for (int nt = 0; nt < 4; nt++)
        bfr[nt] = read_frag(sm.B, wn * 64 + nt * 16 + l16, ks * 4 + quad);
#pragma unroll
      for (int mt = 0; mt < 4; mt++)
#pragma unroll
        for (int nt = 0; nt < 4; nt++)
          acc[mt][nt] = __builtin_amdgcn_mfma_f32_16x16x32_bf16(
              a[mt], bfr[nt], acc[mt][nt], 0, 0, 0);
    }
    __syncthreads();
  }

#pragma unroll
  for (int mt = 0; mt < 4; mt++)
#pragma unroll
    for (int nt = 0; nt < 4; nt++)
#pragma unroll
      for (int r = 0; r < 4; r++) {
        int row = wm * 64 + mt * 16 + quad * 4 + r;
        int d = d0 + wn * 64 + nt * 16 + l16;
        out[((size_t)(b * LSEQ + l0 + row)) * EMBED + d] = acc[mt][nt][r] * zv[row];
      }
}

// ---------------------------------------------------------------------------
// Workspace layout (bytes):
//   xb   @ 0          67,108,864   (bf16 [b][l][d], row-major; alive thru kv)
//   kvp  @ 67108864   33,554,432   (fp32, 4 splits * 8 * 256 * 1024 * 4)
//   wt   @ 134217728   1,048,576   (bf16 [n][k], n=[q|k])
//   qp   @ 135266304  16,777,216   (bf16 [m][e])
//   kT   @ 152043520  16,777,216   (bf16 blocked [b][et][lt][64][64])
//   kvT  @ 168820736   4,194,304   (bf16 [b][d][e])
//   zinv @ 173015040     131,072
// total ~165 MB
// ---------------------------------------------------------------------------
extern "C" void kernel_launch(void* const* d_in, const int* in_sizes, int n_in,
                              void* d_out, int out_size, void* d_ws, size_t ws_size,
                              hipStream_t stream) {
  const float* x  = (const float*)d_in[0];
  const float* qw = (const float*)d_in[1];
  const float* kw = (const float*)d_in[2];
  float* out = (float*)d_out;

  char* ws = (char*)d_ws;
  unsigned short* xb   = (unsigned short*)(ws);
  float*          kvp  = (float*)(ws + 67108864);
  unsigned short* wt   = (unsigned short*)(ws + 134217728);
  unsigned short* qp   = (unsigned short*)(ws + 135266304);
  unsigned short* kT   = (unsigned short*)(ws + 152043520);
  unsigned short* kvT  = (unsigned short*)(ws + 168820736);
  float*          zinv = (float*)(ws + 173015040);

  cvtb_kernel<<<dim3(2048), 256, 0, stream>>>(x, xb);
  cvtw_kernel<<<dim3(4, 16, 2), 256, 0, stream>>>(qw, kw, wt);
  proj_kernel<<<dim3(4, 256), 256, 0, stream>>>(xb, wt, qp, kT);
  zinv_kernel<<<dim3(8192), 256, 0, stream>>>(qp, zinv);
  kv_kernel<<<dim3(8, 2, 32), 256, 0, stream>>>(kT, xb, kvp);
  kvreduce_kernel<<<dim3(16, 4, 8), 256, 0, stream>>>(kvp, kvT);
  out_kernel<<<dim3(8, 32, 8), 256, 0, stream>>>(qp, kvT, zinv, out);
}